// Round 1
// baseline (252.707 us; speedup 1.0000x reference)
//
#include <hip/hip_runtime.h>
#include <hip/hip_bf16.h>

#define H_HEADS 8
#define D_OUT 16
#define C_FEATS 128          // H*D = in-feats = 128
#define NEG_SLOPE 0.2f

// ---------------- GEMM: h = feat @ W  (N x 128 @ 128 x 128) ----------------
// 32 rows/block, 256 threads, feat tile in LDS (row-major, broadcast reads),
// W streamed as float4 (coalesced, L2-resident), 4x4 register blocking.
#define FMA4(acc, f, w0, w1, w2, w3)                                           \
    acc.x = fmaf(f.x, w0.x, fmaf(f.y, w1.x, fmaf(f.z, w2.x, fmaf(f.w, w3.x, acc.x)))); \
    acc.y = fmaf(f.x, w0.y, fmaf(f.y, w1.y, fmaf(f.z, w2.y, fmaf(f.w, w3.y, acc.y)))); \
    acc.z = fmaf(f.x, w0.z, fmaf(f.y, w1.z, fmaf(f.z, w2.z, fmaf(f.w, w3.z, acc.z)))); \
    acc.w = fmaf(f.x, w0.w, fmaf(f.y, w1.w, fmaf(f.z, w2.w, fmaf(f.w, w3.w, acc.w))));

__global__ __launch_bounds__(256) void k_gemm(const float* __restrict__ feat,
                                              const float* __restrict__ W,
                                              float* __restrict__ h, int N) {
    __shared__ float fL[32 * 128];
    const int t = threadIdx.x;
    const int rbase = blockIdx.x * 32;
    {
        const float4* f4 = reinterpret_cast<const float4*>(feat);
        float4* fl4 = reinterpret_cast<float4*>(fL);
#pragma unroll
        for (int i = 0; i < 4; ++i) {
            int idx = t + i * 256;          // float4 index: row = idx>>5, c4 = idx&31
            int r = idx >> 5, c4 = idx & 31;
            int gr = rbase + r;
            float4 v = make_float4(0.f, 0.f, 0.f, 0.f);
            if (gr < N) v = f4[gr * 32 + c4];
            fl4[idx] = v;
        }
    }
    __syncthreads();
    const int cg = t & 31, rg = t >> 5;
    const int c0 = cg * 4, r0 = rg * 4;
    float4 a0 = make_float4(0,0,0,0), a1 = a0, a2 = a0, a3 = a0;
    const float* fp0 = &fL[(r0 + 0) * 128];
    const float* fp1 = &fL[(r0 + 1) * 128];
    const float* fp2 = &fL[(r0 + 2) * 128];
    const float* fp3 = &fL[(r0 + 3) * 128];
#pragma unroll 4
    for (int k = 0; k < 128; k += 4) {
        float4 w0 = *reinterpret_cast<const float4*>(&W[(k + 0) * 128 + c0]);
        float4 w1 = *reinterpret_cast<const float4*>(&W[(k + 1) * 128 + c0]);
        float4 w2 = *reinterpret_cast<const float4*>(&W[(k + 2) * 128 + c0]);
        float4 w3 = *reinterpret_cast<const float4*>(&W[(k + 3) * 128 + c0]);
        float4 f0 = *reinterpret_cast<const float4*>(&fp0[k]);
        float4 f1 = *reinterpret_cast<const float4*>(&fp1[k]);
        float4 f2 = *reinterpret_cast<const float4*>(&fp2[k]);
        float4 f3 = *reinterpret_cast<const float4*>(&fp3[k]);
        FMA4(a0, f0, w0, w1, w2, w3)
        FMA4(a1, f1, w0, w1, w2, w3)
        FMA4(a2, f2, w0, w1, w2, w3)
        FMA4(a3, f3, w0, w1, w2, w3)
    }
    int gr = rbase + r0;
    if (gr + 0 < N) *reinterpret_cast<float4*>(&h[(gr + 0) * 128 + c0]) = a0;
    if (gr + 1 < N) *reinterpret_cast<float4*>(&h[(gr + 1) * 128 + c0]) = a1;
    if (gr + 2 < N) *reinterpret_cast<float4*>(&h[(gr + 2) * 128 + c0]) = a2;
    if (gr + 3 < N) *reinterpret_cast<float4*>(&h[(gr + 3) * 128 + c0]) = a3;
}

// ---------------- per-node logits: es[n,h], ed[n,h] ----------------
__global__ void k_logits(const float* __restrict__ h, const float* __restrict__ aw,
                         float* __restrict__ es, float* __restrict__ ed, int N) {
    int idx = blockIdx.x * 256 + threadIdx.x;   // (n, head)
    if (idx >= N * H_HEADS) return;
    int n = idx >> 3, hh = idx & 7;
    const float4* hv = reinterpret_cast<const float4*>(&h[n * C_FEATS + hh * D_OUT]);
    const float4* p0 = reinterpret_cast<const float4*>(&aw[hh * D_OUT]);
    const float4* p1 = reinterpret_cast<const float4*>(&aw[C_FEATS + hh * D_OUT]);
    float s0 = 0.f, s1 = 0.f;
#pragma unroll
    for (int j = 0; j < 4; ++j) {
        float4 x = hv[j];
        float4 a = p0[j];
        float4 b = p1[j];
        s0 += x.x * a.x + x.y * a.y + x.z * a.z + x.w * a.w;
        s1 += x.x * b.x + x.y * b.y + x.z * b.z + x.w * b.w;
    }
    es[idx] = s0;
    ed[idx] = s1;
}

// ---------------- degree count ----------------
__global__ void k_deg(const int* __restrict__ dst, int* __restrict__ deg, int E) {
    int e = blockIdx.x * 256 + threadIdx.x;
    if (e < E) atomicAdd(&deg[dst[e]], 1);
}

// ---------------- scan helpers ----------------
__device__ inline int block_scan_incl(int v) {
    int lane = threadIdx.x & 63, w = threadIdx.x >> 6;
    int x = v;
#pragma unroll
    for (int d = 1; d < 64; d <<= 1) {
        int u = __shfl_up(x, d, 64);
        if (lane >= d) x += u;
    }
    __shared__ int wsum[4];
    if (lane == 63) wsum[w] = x;
    __syncthreads();
    int add = 0;
    for (int k = 0; k < w; ++k) add += wsum[k];
    return x + add;
}

__global__ void k_bsum(const int* __restrict__ deg, int* __restrict__ bsum, int N) {
    int i = blockIdx.x * 256 + threadIdx.x;
    int v = (i < N) ? deg[i] : 0;
#pragma unroll
    for (int m = 1; m < 64; m <<= 1) v += __shfl_xor(v, m, 64);
    __shared__ int ws[4];
    if ((threadIdx.x & 63) == 0) ws[threadIdx.x >> 6] = v;
    __syncthreads();
    if (threadIdx.x == 0) bsum[blockIdx.x] = ws[0] + ws[1] + ws[2] + ws[3];
}

// single block; NB <= 256
__global__ void k_scanb(const int* __restrict__ bsum, int* __restrict__ bpre,
                        int NB, int* __restrict__ offs, int N) {
    int t = threadIdx.x;
    int v = (t < NB) ? bsum[t] : 0;
    int incl = block_scan_incl(v);
    if (t < NB) bpre[t] = incl - v;
    if (t == NB - 1) offs[N] = incl;
}

__global__ void k_scanc(const int* __restrict__ deg, const int* __restrict__ bpre,
                        int* __restrict__ offs, int* __restrict__ cursor, int N) {
    int i = blockIdx.x * 256 + threadIdx.x;
    int v = (i < N) ? deg[i] : 0;
    int incl = block_scan_incl(v);
    int excl = incl - v + bpre[blockIdx.x];
    if (i < N) { offs[i] = excl; cursor[i] = excl; }
}

// ---------------- scatter src ids into CSR slots ----------------
__global__ void k_scatter(const int* __restrict__ src, const int* __restrict__ dst,
                          int* __restrict__ cursor, int* __restrict__ ssorted, int E) {
    int e = blockIdx.x * 256 + threadIdx.x;
    if (e < E) {
        int d = dst[e];
        int pos = atomicAdd(&cursor[d], 1);
        ssorted[pos] = src[e];
    }
}

// ---------------- per-node softmax + aggregation (one wave per node) --------
__global__ __launch_bounds__(256) void k_agg(const float* __restrict__ h,
                                             const float* __restrict__ es,
                                             const float* __restrict__ ed,
                                             const int* __restrict__ offs,
                                             const int* __restrict__ ssorted,
                                             const float* __restrict__ bias,
                                             float* __restrict__ out, int N) {
    int wid = threadIdx.x >> 6, lane = threadIdx.x & 63;
    int n = blockIdx.x * 4 + wid;
    if (n >= N) return;
    int beg = offs[n];
    int deg = offs[n + 1] - beg;

    // pass 1: per-head (m, sumexp); lane = head*8 + j, edges strided by 8
    int hh = lane >> 3;
    int j0 = lane & 7;
    float edv = ed[n * H_HEADS + hh];
    float m = -1e30f, s = 0.f;
    for (int e = j0; e < deg; e += 8) {
        int sn = ssorted[beg + e];
        float ev = es[sn * H_HEADS + hh] + edv;
        ev = ev > 0.f ? ev : NEG_SLOPE * ev;
        if (ev > m) {
            s = s * __expf(m - ev) + 1.f;
            m = ev;
        } else {
            s += __expf(ev - m);
        }
    }
#pragma unroll
    for (int msk = 1; msk < 8; msk <<= 1) {
        float mo = __shfl_xor(m, msk, 64);
        float so = __shfl_xor(s, msk, 64);
        float mn = fmaxf(m, mo);
        s = s * __expf(m - mn) + so * __expf(mo - mn);
        m = mn;
    }
    // pass 2: each lane accumulates cols (lane, lane+64)
    int c1 = lane, c2 = lane + 64;
    int h1 = lane >> 4, h2 = 4 + (lane >> 4);
    float m1 = __shfl(m, h1 * 8, 64), s1 = __shfl(s, h1 * 8, 64);
    float m2 = __shfl(m, h2 * 8, 64), s2 = __shfl(s, h2 * 8, 64);
    float inv1 = (s1 > 0.f) ? 1.f / s1 : 0.f;
    float inv2 = (s2 > 0.f) ? 1.f / s2 : 0.f;
    float ed1 = ed[n * H_HEADS + h1], ed2 = ed[n * H_HEADS + h2];
    float acc1 = 0.f, acc2 = 0.f;
    for (int e = 0; e < deg; ++e) {
        int sn = ssorted[beg + e];
        float ev1 = es[sn * H_HEADS + h1] + ed1;
        float ev2 = es[sn * H_HEADS + h2] + ed2;
        ev1 = ev1 > 0.f ? ev1 : NEG_SLOPE * ev1;
        ev2 = ev2 > 0.f ? ev2 : NEG_SLOPE * ev2;
        float al1 = __expf(ev1 - m1) * inv1;
        float al2 = __expf(ev2 - m2) * inv2;
        acc1 = fmaf(al1, h[sn * C_FEATS + c1], acc1);
        acc2 = fmaf(al2, h[sn * C_FEATS + c2], acc2);
    }
    out[n * C_FEATS + c1] = acc1 + bias[c1];
    out[n * C_FEATS + c2] = acc2 + bias[c2];
}

extern "C" void kernel_launch(void* const* d_in, const int* in_sizes, int n_in,
                              void* d_out, int out_size, void* d_ws, size_t ws_size,
                              hipStream_t stream) {
    const float* feat = (const float*)d_in[0];
    const float* W    = (const float*)d_in[1];
    const float* aw   = (const float*)d_in[2];
    const float* bias = (const float*)d_in[3];
    const int*   src  = (const int*)d_in[4];
    const int*   dst  = (const int*)d_in[5];
    float* out = (float*)d_out;

    const int N = in_sizes[0] / C_FEATS;
    const int E = in_sizes[4];
    const int NB = (N + 255) / 256;   // must be <= 256 (N=50000 -> 196)

    // workspace layout (all 4-byte elems, 256B-aligned sections)
    char* p = (char*)d_ws;
    auto take = [&](size_t bytes) {
        char* q = p;
        p += (bytes + 255) & ~size_t(255);
        return q;
    };
    float* h_buf   = (float*)take((size_t)N * C_FEATS * 4);
    float* es      = (float*)take((size_t)N * H_HEADS * 4);
    float* edt     = (float*)take((size_t)N * H_HEADS * 4);
    int*   deg     = (int*)take((size_t)N * 4);
    int*   offs    = (int*)take((size_t)(N + 1) * 4);
    int*   cursor  = (int*)take((size_t)N * 4);
    int*   bsum    = (int*)take((size_t)NB * 4);
    int*   bpre    = (int*)take((size_t)NB * 4);
    int*   ssorted = (int*)take((size_t)E * 4);
    (void)ws_size;

    hipMemsetAsync(deg, 0, (size_t)N * 4, stream);

    k_gemm<<<(N + 31) / 32, 256, 0, stream>>>(feat, W, h_buf, N);
    k_logits<<<(N * H_HEADS + 255) / 256, 256, 0, stream>>>(h_buf, aw, es, edt, N);
    k_deg<<<(E + 255) / 256, 256, 0, stream>>>(dst, deg, E);
    k_bsum<<<NB, 256, 0, stream>>>(deg, bsum, N);
    k_scanb<<<1, 256, 0, stream>>>(bsum, bpre, NB, offs, N);
    k_scanc<<<NB, 256, 0, stream>>>(deg, bpre, offs, cursor, N);
    k_scatter<<<(E + 255) / 256, 256, 0, stream>>>(src, dst, cursor, ssorted, E);
    k_agg<<<(N + 3) / 4, 256, 0, stream>>>(h_buf, es, edt, offs, ssorted, bias, out, N);
}

// Round 2
// 221.462 us; speedup vs baseline: 1.1411x; 1.1411x over previous
//
#include <hip/hip_runtime.h>
#include <hip/hip_bf16.h>

#define H_HEADS 8
#define D_OUT 16
#define C_FEATS 128          // H*D = in-feats = 128
#define NEG_SLOPE 0.2f

// ---------------- GEMM: h = feat @ W  (N x 128 @ 128 x 128) ----------------
#define FMA4(acc, f, w0, w1, w2, w3)                                           \
    acc.x = fmaf(f.x, w0.x, fmaf(f.y, w1.x, fmaf(f.z, w2.x, fmaf(f.w, w3.x, acc.x)))); \
    acc.y = fmaf(f.x, w0.y, fmaf(f.y, w1.y, fmaf(f.z, w2.y, fmaf(f.w, w3.y, acc.y)))); \
    acc.z = fmaf(f.x, w0.z, fmaf(f.y, w1.z, fmaf(f.z, w2.z, fmaf(f.w, w3.z, acc.z)))); \
    acc.w = fmaf(f.x, w0.w, fmaf(f.y, w1.w, fmaf(f.z, w2.w, fmaf(f.w, w3.w, acc.w))));

__global__ __launch_bounds__(256) void k_gemm(const float* __restrict__ feat,
                                              const float* __restrict__ W,
                                              float* __restrict__ h, int N) {
    __shared__ float fL[32 * 128];
    const int t = threadIdx.x;
    const int rbase = blockIdx.x * 32;
    {
        const float4* f4 = reinterpret_cast<const float4*>(feat);
        float4* fl4 = reinterpret_cast<float4*>(fL);
#pragma unroll
        for (int i = 0; i < 4; ++i) {
            int idx = t + i * 256;
            int r = idx >> 5, c4 = idx & 31;
            int gr = rbase + r;
            float4 v = make_float4(0.f, 0.f, 0.f, 0.f);
            if (gr < N) v = f4[gr * 32 + c4];
            fl4[idx] = v;
        }
    }
    __syncthreads();
    const int cg = t & 31, rg = t >> 5;
    const int c0 = cg * 4, r0 = rg * 4;
    float4 a0 = make_float4(0,0,0,0), a1 = a0, a2 = a0, a3 = a0;
    const float* fp0 = &fL[(r0 + 0) * 128];
    const float* fp1 = &fL[(r0 + 1) * 128];
    const float* fp2 = &fL[(r0 + 2) * 128];
    const float* fp3 = &fL[(r0 + 3) * 128];
#pragma unroll 4
    for (int k = 0; k < 128; k += 4) {
        float4 w0 = *reinterpret_cast<const float4*>(&W[(k + 0) * 128 + c0]);
        float4 w1 = *reinterpret_cast<const float4*>(&W[(k + 1) * 128 + c0]);
        float4 w2 = *reinterpret_cast<const float4*>(&W[(k + 2) * 128 + c0]);
        float4 w3 = *reinterpret_cast<const float4*>(&W[(k + 3) * 128 + c0]);
        float4 f0 = *reinterpret_cast<const float4*>(&fp0[k]);
        float4 f1 = *reinterpret_cast<const float4*>(&fp1[k]);
        float4 f2 = *reinterpret_cast<const float4*>(&fp2[k]);
        float4 f3 = *reinterpret_cast<const float4*>(&fp3[k]);
        FMA4(a0, f0, w0, w1, w2, w3)
        FMA4(a1, f1, w0, w1, w2, w3)
        FMA4(a2, f2, w0, w1, w2, w3)
        FMA4(a3, f3, w0, w1, w2, w3)
    }
    int gr = rbase + r0;
    if (gr + 0 < N) *reinterpret_cast<float4*>(&h[(gr + 0) * 128 + c0]) = a0;
    if (gr + 1 < N) *reinterpret_cast<float4*>(&h[(gr + 1) * 128 + c0]) = a1;
    if (gr + 2 < N) *reinterpret_cast<float4*>(&h[(gr + 2) * 128 + c0]) = a2;
    if (gr + 3 < N) *reinterpret_cast<float4*>(&h[(gr + 3) * 128 + c0]) = a3;
}

// ---------------- per-node logits: es[n,h], ed[n,h] ----------------
__global__ void k_logits(const float* __restrict__ h, const float* __restrict__ aw,
                         float* __restrict__ es, float* __restrict__ ed, int N) {
    int idx = blockIdx.x * 256 + threadIdx.x;   // (n, head)
    if (idx >= N * H_HEADS) return;
    int n = idx >> 3, hh = idx & 7;
    const float4* hv = reinterpret_cast<const float4*>(&h[n * C_FEATS + hh * D_OUT]);
    const float4* p0 = reinterpret_cast<const float4*>(&aw[hh * D_OUT]);
    const float4* p1 = reinterpret_cast<const float4*>(&aw[C_FEATS + hh * D_OUT]);
    float s0 = 0.f, s1 = 0.f;
#pragma unroll
    for (int j = 0; j < 4; ++j) {
        float4 x = hv[j];
        float4 a = p0[j];
        float4 b = p1[j];
        s0 += x.x * a.x + x.y * a.y + x.z * a.z + x.w * a.w;
        s1 += x.x * b.x + x.y * b.y + x.z * b.z + x.w * b.w;
    }
    es[idx] = s0;
    ed[idx] = s1;
}

// ---------------- degree count ----------------
__global__ void k_deg(const int* __restrict__ dst, int* __restrict__ deg, int E) {
    int e = blockIdx.x * 256 + threadIdx.x;
    if (e < E) atomicAdd(&deg[dst[e]], 1);
}

// ---------------- scan helpers ----------------
__device__ inline int block_scan_incl(int v) {
    int lane = threadIdx.x & 63, w = threadIdx.x >> 6;
    int x = v;
#pragma unroll
    for (int d = 1; d < 64; d <<= 1) {
        int u = __shfl_up(x, d, 64);
        if (lane >= d) x += u;
    }
    __shared__ int wsum[4];
    if (lane == 63) wsum[w] = x;
    __syncthreads();
    int add = 0;
    for (int k = 0; k < w; ++k) add += wsum[k];
    return x + add;
}

__global__ void k_bsum(const int* __restrict__ deg, int* __restrict__ bsum, int N) {
    int i = blockIdx.x * 256 + threadIdx.x;
    int v = (i < N) ? deg[i] : 0;
#pragma unroll
    for (int m = 1; m < 64; m <<= 1) v += __shfl_xor(v, m, 64);
    __shared__ int ws[4];
    if ((threadIdx.x & 63) == 0) ws[threadIdx.x >> 6] = v;
    __syncthreads();
    if (threadIdx.x == 0) bsum[blockIdx.x] = ws[0] + ws[1] + ws[2] + ws[3];
}

// single block; NB <= 256
__global__ void k_scanb(const int* __restrict__ bsum, int* __restrict__ bpre,
                        int NB, int* __restrict__ offs, int N) {
    int t = threadIdx.x;
    int v = (t < NB) ? bsum[t] : 0;
    int incl = block_scan_incl(v);
    if (t < NB) bpre[t] = incl - v;
    if (t == NB - 1) offs[N] = incl;
}

__global__ void k_scanc(const int* __restrict__ deg, const int* __restrict__ bpre,
                        int* __restrict__ offs, int* __restrict__ cursor, int N) {
    int i = blockIdx.x * 256 + threadIdx.x;
    int v = (i < N) ? deg[i] : 0;
    int incl = block_scan_incl(v);
    int excl = incl - v + bpre[blockIdx.x];
    if (i < N) { offs[i] = excl; cursor[i] = excl; }
}

// ---------------- scatter src ids into CSR slots ----------------
__global__ void k_scatter(const int* __restrict__ src, const int* __restrict__ dst,
                          int* __restrict__ cursor, int* __restrict__ ssorted, int E) {
    int e = blockIdx.x * 256 + threadIdx.x;
    if (e < E) {
        int d = dst[e];
        int pos = atomicAdd(&cursor[d], 1);
        ssorted[pos] = src[e];
    }
}

// ---------------- per-node softmax + aggregation (one wave per node) --------
// Phase A: per-head online (m, sumexp), lane = head*8 + j over edge strides of 8.
// Phase B: chunks of 8 edges; alpha computed once per (edge,head) by the phase-A
// lane layout (1 exp / lane / chunk), distributed via ds_bpermute; accumulation
// is half-wave-per-edge with float4 columns (1 dwordx4 per lane covers 2 edges).
__global__ __launch_bounds__(256) void k_agg(const float* __restrict__ h,
                                             const float* __restrict__ es,
                                             const float* __restrict__ ed,
                                             const int* __restrict__ offs,
                                             const int* __restrict__ ssorted,
                                             const float* __restrict__ bias,
                                             float* __restrict__ out, int N) {
    int wid = threadIdx.x >> 6, lane = threadIdx.x & 63;
    int n = blockIdx.x * 4 + wid;
    if (n >= N) return;
    int beg = offs[n];
    int deg = offs[n + 1] - beg;

    const int hh = lane >> 3;       // phase-A head for this lane
    const int j0 = lane & 7;        // phase-A edge slot within chunk
    float edv = ed[n * H_HEADS + hh];

    // ---- Phase A: online softmax stats per head ----
    float m = -1e30f, s = 0.f;
    for (int e = j0; e < deg; e += 8) {
        int sn = ssorted[beg + e];
        float ev = es[sn * H_HEADS + hh] + edv;
        ev = ev > 0.f ? ev : NEG_SLOPE * ev;
        if (ev > m) {
            s = s * __expf(m - ev) + 1.f;
            m = ev;
        } else {
            s += __expf(ev - m);
        }
    }
#pragma unroll
    for (int msk = 1; msk < 8; msk <<= 1) {
        float mo = __shfl_xor(m, msk, 64);
        float so = __shfl_xor(s, msk, 64);
        float mn = fmaxf(m, mo);
        s = s * __expf(m - mn) + so * __expf(mo - mn);
        m = mn;
    }
    float inv = (s > 0.f) ? 1.f / s : 0.f;

    // ---- Phase B: chunks of 8 edges ----
    // accumulation layout: half = lane>>5 (edge parity), cols 4*(lane&31)..+3
    const int cl = lane & 31;            // column-group id (0..31)
    const int half = lane >> 5;          // 0: even edge, 1: odd edge
    const int ibase = ((cl >> 2) << 3) + half;  // bpermute base: head*8 + parity
    float4 acc = make_float4(0.f, 0.f, 0.f, 0.f);

    for (int cb = 0; cb < deg; cb += 8) {
        int j = cb + j0;
        int sn = 0;
        float alpha = 0.f;
        if (j < deg) {
            sn = ssorted[beg + j];
            float ev = es[sn * H_HEADS + hh] + edv;
            ev = ev > 0.f ? ev : NEG_SLOPE * ev;
            alpha = __expf(ev - m) * inv;
        }
        int rem = deg - cb; if (rem > 8) rem = 8;
#pragma unroll
        for (int e2 = 0; e2 < 4; ++e2) {
            if (2 * e2 >= rem) break;
            int sn0 = __shfl(sn, 2 * e2, 64);
            int sn1 = __shfl(sn, 2 * e2 + 1, 64);
            int snm = half ? sn1 : sn0;
            float al = __shfl(alpha, ibase + 2 * e2, 64);
            float4 hv = *reinterpret_cast<const float4*>(&h[(size_t)snm * C_FEATS + cl * 4]);
            acc.x = fmaf(al, hv.x, acc.x);
            acc.y = fmaf(al, hv.y, acc.y);
            acc.z = fmaf(al, hv.z, acc.z);
            acc.w = fmaf(al, hv.w, acc.w);
        }
    }
    // combine the two halves (same columns) and store 512B coalesced
    acc.x += __shfl_xor(acc.x, 32, 64);
    acc.y += __shfl_xor(acc.y, 32, 64);
    acc.z += __shfl_xor(acc.z, 32, 64);
    acc.w += __shfl_xor(acc.w, 32, 64);
    if (half == 0) {
        const float4 bv = *reinterpret_cast<const float4*>(&bias[cl * 4]);
        float4 o = make_float4(acc.x + bv.x, acc.y + bv.y, acc.z + bv.z, acc.w + bv.w);
        *reinterpret_cast<float4*>(&out[(size_t)n * C_FEATS + cl * 4]) = o;
    }
}

extern "C" void kernel_launch(void* const* d_in, const int* in_sizes, int n_in,
                              void* d_out, int out_size, void* d_ws, size_t ws_size,
                              hipStream_t stream) {
    const float* feat = (const float*)d_in[0];
    const float* W    = (const float*)d_in[1];
    const float* aw   = (const float*)d_in[2];
    const float* bias = (const float*)d_in[3];
    const int*   src  = (const int*)d_in[4];
    const int*   dst  = (const int*)d_in[5];
    float* out = (float*)d_out;

    const int N = in_sizes[0] / C_FEATS;
    const int E = in_sizes[4];
    const int NB = (N + 255) / 256;   // must be <= 256 (N=50000 -> 196)

    char* p = (char*)d_ws;
    auto take = [&](size_t bytes) {
        char* q = p;
        p += (bytes + 255) & ~size_t(255);
        return q;
    };
    float* h_buf   = (float*)take((size_t)N * C_FEATS * 4);
    float* es      = (float*)take((size_t)N * H_HEADS * 4);
    float* edt     = (float*)take((size_t)N * H_HEADS * 4);
    int*   deg     = (int*)take((size_t)N * 4);
    int*   offs    = (int*)take((size_t)(N + 1) * 4);
    int*   cursor  = (int*)take((size_t)N * 4);
    int*   bsum    = (int*)take((size_t)NB * 4);
    int*   bpre    = (int*)take((size_t)NB * 4);
    int*   ssorted = (int*)take((size_t)E * 4);
    (void)ws_size;

    hipMemsetAsync(deg, 0, (size_t)N * 4, stream);

    k_gemm<<<(N + 31) / 32, 256, 0, stream>>>(feat, W, h_buf, N);
    k_logits<<<(N * H_HEADS + 255) / 256, 256, 0, stream>>>(h_buf, aw, es, edt, N);
    k_deg<<<(E + 255) / 256, 256, 0, stream>>>(dst, deg, E);
    k_bsum<<<NB, 256, 0, stream>>>(deg, bsum, N);
    k_scanb<<<1, 256, 0, stream>>>(bsum, bpre, NB, offs, N);
    k_scanc<<<NB, 256, 0, stream>>>(deg, bpre, offs, cursor, N);
    k_scatter<<<(E + 255) / 256, 256, 0, stream>>>(src, dst, cursor, ssorted, E);
    k_agg<<<(N + 3) / 4, 256, 0, stream>>>(h_buf, es, edt, offs, ssorted, bias, out, N);
}

// Round 5
// 187.474 us; speedup vs baseline: 1.3480x; 1.1813x over previous
//
#include <hip/hip_runtime.h>
#include <hip/hip_bf16.h>

#define H_HEADS 8
#define D_OUT 16
#define C_FEATS 128          // H*D = in-feats = 128
#define NEG_SLOPE 0.2f

__device__ inline unsigned short f2bf(float f) {
    __hip_bfloat16 b = __float2bfloat16(f);
    return *reinterpret_cast<unsigned short*>(&b);
}
__device__ inline float bf_lo(unsigned u) { return __uint_as_float(u << 16); }
__device__ inline float bf_hi(unsigned u) { return __uint_as_float(u & 0xffff0000u); }

// ---------------- GEMM + logits fused ----------------
// h16 = bf16(feat @ W); es/ed = per-node per-head attention logits (f32 path).
#define FMA4(acc, f, w0, w1, w2, w3)                                           \
    acc.x = fmaf(f.x, w0.x, fmaf(f.y, w1.x, fmaf(f.z, w2.x, fmaf(f.w, w3.x, acc.x)))); \
    acc.y = fmaf(f.x, w0.y, fmaf(f.y, w1.y, fmaf(f.z, w2.y, fmaf(f.w, w3.y, acc.y)))); \
    acc.z = fmaf(f.x, w0.z, fmaf(f.y, w1.z, fmaf(f.z, w2.z, fmaf(f.w, w3.z, acc.z)))); \
    acc.w = fmaf(f.x, w0.w, fmaf(f.y, w1.w, fmaf(f.z, w2.w, fmaf(f.w, w3.w, acc.w))));

__global__ __launch_bounds__(256) void k_gemm(const float* __restrict__ feat,
                                              const float* __restrict__ W,
                                              const float* __restrict__ aw,
                                              unsigned short* __restrict__ h16,
                                              float* __restrict__ es,
                                              float* __restrict__ ed, int N) {
    __shared__ float fL[32 * 128];
    const int t = threadIdx.x;
    const int rbase = blockIdx.x * 32;
    {
        const float4* f4 = reinterpret_cast<const float4*>(feat);
        float4* fl4 = reinterpret_cast<float4*>(fL);
#pragma unroll
        for (int i = 0; i < 4; ++i) {
            int idx = t + i * 256;
            int r = idx >> 5, c4 = idx & 31;
            int gr = rbase + r;
            float4 v = make_float4(0.f, 0.f, 0.f, 0.f);
            if (gr < N) v = f4[gr * 32 + c4];
            fl4[idx] = v;
        }
    }
    __syncthreads();
    const int cg = t & 31, rg = t >> 5;
    const int c0 = cg * 4, r0 = rg * 4;
    float4 a0 = make_float4(0,0,0,0), a1 = a0, a2 = a0, a3 = a0;
    const float* fp0 = &fL[(r0 + 0) * 128];
    const float* fp1 = &fL[(r0 + 1) * 128];
    const float* fp2 = &fL[(r0 + 2) * 128];
    const float* fp3 = &fL[(r0 + 3) * 128];
#pragma unroll 4
    for (int k = 0; k < 128; k += 4) {
        float4 w0 = *reinterpret_cast<const float4*>(&W[(k + 0) * 128 + c0]);
        float4 w1 = *reinterpret_cast<const float4*>(&W[(k + 1) * 128 + c0]);
        float4 w2 = *reinterpret_cast<const float4*>(&W[(k + 2) * 128 + c0]);
        float4 w3 = *reinterpret_cast<const float4*>(&W[(k + 3) * 128 + c0]);
        float4 f0 = *reinterpret_cast<const float4*>(&fp0[k]);
        float4 f1 = *reinterpret_cast<const float4*>(&fp1[k]);
        float4 f2 = *reinterpret_cast<const float4*>(&fp2[k]);
        float4 f3 = *reinterpret_cast<const float4*>(&fp3[k]);
        FMA4(a0, f0, w0, w1, w2, w3)
        FMA4(a1, f1, w0, w1, w2, w3)
        FMA4(a2, f2, w0, w1, w2, w3)
        FMA4(a3, f3, w0, w1, w2, w3)
    }
    const int gr = rbase + r0;
#pragma unroll
    for (int i = 0; i < 4; ++i) {
        float4 a = (i == 0) ? a0 : (i == 1) ? a1 : (i == 2) ? a2 : a3;
        if (gr + i < N) {
            ushort4 p;
            p.x = f2bf(a.x); p.y = f2bf(a.y); p.z = f2bf(a.z); p.w = f2bf(a.w);
            *reinterpret_cast<ushort4*>(&h16[(size_t)(gr + i) * C_FEATS + c0]) = p;
        }
    }
    // logits epilogue: partial dots vs attn weights, reduce over 4-lane col groups
    const float4 w0v = *reinterpret_cast<const float4*>(&aw[c0]);
    const float4 w1v = *reinterpret_cast<const float4*>(&aw[C_FEATS + c0]);
    float esv[4], edv[4];
#pragma unroll
    for (int i = 0; i < 4; ++i) {
        float4 a = (i == 0) ? a0 : (i == 1) ? a1 : (i == 2) ? a2 : a3;
        esv[i] = a.x * w0v.x + a.y * w0v.y + a.z * w0v.z + a.w * w0v.w;
        edv[i] = a.x * w1v.x + a.y * w1v.y + a.z * w1v.z + a.w * w1v.w;
    }
#pragma unroll
    for (int msk = 1; msk <= 2; msk <<= 1) {
#pragma unroll
        for (int i = 0; i < 4; ++i) {
            esv[i] += __shfl_xor(esv[i], msk, 64);
            edv[i] += __shfl_xor(edv[i], msk, 64);
        }
    }
    if ((cg & 3) == 0) {
        const int head = cg >> 2;
#pragma unroll
        for (int i = 0; i < 4; ++i) {
            if (gr + i < N) {
                es[(size_t)(gr + i) * H_HEADS + head] = esv[i];
                ed[(size_t)(gr + i) * H_HEADS + head] = edv[i];
            }
        }
    }
}

// ---------------- degree count ----------------
__global__ void k_deg(const int* __restrict__ dst, int* __restrict__ deg, int E) {
    int e = blockIdx.x * 256 + threadIdx.x;
    if (e < E) atomicAdd(&deg[dst[e]], 1);
}

// ---------------- scan helpers ----------------
__device__ inline int block_scan_incl(int v) {
    int lane = threadIdx.x & 63, w = threadIdx.x >> 6;
    int x = v;
#pragma unroll
    for (int d = 1; d < 64; d <<= 1) {
        int u = __shfl_up(x, d, 64);
        if (lane >= d) x += u;
    }
    __shared__ int wsum[4];
    if (lane == 63) wsum[w] = x;
    __syncthreads();
    int add = 0;
    for (int k = 0; k < w; ++k) add += wsum[k];
    return x + add;
}

__global__ void k_bsum(const int* __restrict__ deg, int* __restrict__ bsum, int N) {
    int i = blockIdx.x * 256 + threadIdx.x;
    int v = (i < N) ? deg[i] : 0;
#pragma unroll
    for (int m = 1; m < 64; m <<= 1) v += __shfl_xor(v, m, 64);
    __shared__ int ws[4];
    if ((threadIdx.x & 63) == 0) ws[threadIdx.x >> 6] = v;
    __syncthreads();
    if (threadIdx.x == 0) bsum[blockIdx.x] = ws[0] + ws[1] + ws[2] + ws[3];
}

__global__ void k_scanb(const int* __restrict__ bsum, int* __restrict__ bpre,
                        int NB, int* __restrict__ offs, int N) {
    int t = threadIdx.x;
    int v = (t < NB) ? bsum[t] : 0;
    int incl = block_scan_incl(v);
    if (t < NB) bpre[t] = incl - v;
    if (t == NB - 1) offs[N] = incl;
}

__global__ void k_scanc(const int* __restrict__ deg, const int* __restrict__ bpre,
                        int* __restrict__ offs, int* __restrict__ cursor, int N) {
    int i = blockIdx.x * 256 + threadIdx.x;
    int v = (i < N) ? deg[i] : 0;
    int incl = block_scan_incl(v);
    int excl = incl - v + bpre[blockIdx.x];
    if (i < N) { offs[i] = excl; cursor[i] = excl; }
}

__global__ void k_scatter(const int* __restrict__ src, const int* __restrict__ dst,
                          int* __restrict__ cursor, int* __restrict__ ssorted, int E) {
    int e = blockIdx.x * 256 + threadIdx.x;
    if (e < E) {
        int d = dst[e];
        int pos = atomicAdd(&cursor[d], 1);
        ssorted[pos] = src[e];
    }
}

// ---------------- two-pass softmax + aggregation (R2-proven structure) -------
// One wave per node. Phase A: per-head online (m,s), lane = hh*8+j0, stride 8.
// Phase B: chunks of 8 edges; alpha = exp(ev - m)/s computed once per
// (edge,head) in the softmax layout (1 exp/lane/chunk); sn via constant-index
// shuffles + select; alpha via bpermute (alpha=0 covers the tail). Gather:
// cl = lane&15 owns 8 bf16 cols (uint4 16B), q = lane>>4 -> 4 edges parallel.
__global__ __launch_bounds__(256) void k_agg(const unsigned short* __restrict__ h16,
                                             const float* __restrict__ es,
                                             const float* __restrict__ ed,
                                             const int* __restrict__ offs,
                                             const int* __restrict__ ssorted,
                                             const float* __restrict__ bias,
                                             float* __restrict__ out, int N) {
    const int wid = threadIdx.x >> 6, lane = threadIdx.x & 63;
    const int n = blockIdx.x * 4 + wid;
    if (n >= N) return;
    const int beg = offs[n];
    const int deg = offs[n + 1] - beg;

    const int hh = lane >> 3, j0 = lane & 7;
    const float edv = ed[(size_t)n * H_HEADS + hh];

    // ---- Phase A: online softmax stats per head ----
    float m = -1e30f, s = 0.f;
    for (int e = j0; e < deg; e += 8) {
        int sn = ssorted[beg + e];
        float ev = es[(size_t)sn * H_HEADS + hh] + edv;
        ev = ev > 0.f ? ev : NEG_SLOPE * ev;
        if (ev > m) {
            s = s * __expf(m - ev) + 1.f;
            m = ev;
        } else {
            s += __expf(ev - m);
        }
    }
#pragma unroll
    for (int msk = 1; msk < 8; msk <<= 1) {
        float mo = __shfl_xor(m, msk, 64);
        float so = __shfl_xor(s, msk, 64);
        float mn = fmaxf(m, mo);
        s = s * __expf(m - mn) + so * __expf(mo - mn);
        m = mn;
    }
    const float inv = (s > 0.f) ? 1.f / s : 0.f;

    // ---- Phase B ----
    const int cl = lane & 15, q = lane >> 4;
    const int ah = cl >> 1;             // head owning this lane's 8 columns
    const int ab = ah << 3;             // softmax-layout base lane for head ah
    float acc[8];
#pragma unroll
    for (int k = 0; k < 8; ++k) acc[k] = 0.f;

    for (int cb = 0; cb < deg; cb += 8) {
        const int j = cb + j0;
        int sn = 0;
        float alpha = 0.f;
        if (j < deg) {
            sn = ssorted[beg + j];
            float t = es[(size_t)sn * H_HEADS + hh] + edv;
            t = t > 0.f ? t : NEG_SLOPE * t;
            alpha = __expf(t - m) * inv;    // final normalized weight
        }
        int rem = deg - cb; if (rem > 8) rem = 8;
#pragma unroll
        for (int e4 = 0; e4 < 2; ++e4) {
            if (4 * e4 >= rem) break;       // uniform exit
            const int s0 = __shfl(sn, 4 * e4 + 0, 64);
            const int s1 = __shfl(sn, 4 * e4 + 1, 64);
            const int s2 = __shfl(sn, 4 * e4 + 2, 64);
            const int s3 = __shfl(sn, 4 * e4 + 3, 64);
            const int snq = (q == 0) ? s0 : (q == 1) ? s1 : (q == 2) ? s2 : s3;
            const float al = __shfl(alpha, ab + 4 * e4 + q, 64); // 0 for OOB tail
            const uint4 hv = *reinterpret_cast<const uint4*>(
                &h16[(size_t)snq * C_FEATS + cl * 8]);
            acc[0] = fmaf(al, bf_lo(hv.x), acc[0]);
            acc[1] = fmaf(al, bf_hi(hv.x), acc[1]);
            acc[2] = fmaf(al, bf_lo(hv.y), acc[2]);
            acc[3] = fmaf(al, bf_hi(hv.y), acc[3]);
            acc[4] = fmaf(al, bf_lo(hv.z), acc[4]);
            acc[5] = fmaf(al, bf_hi(hv.z), acc[5]);
            acc[6] = fmaf(al, bf_lo(hv.w), acc[6]);
            acc[7] = fmaf(al, bf_hi(hv.w), acc[7]);
        }
    }
#pragma unroll
    for (int k = 0; k < 8; ++k) {
        acc[k] += __shfl_xor(acc[k], 16, 64);
        acc[k] += __shfl_xor(acc[k], 32, 64);
    }
    if (q == 0) {
        const float4 b0 = *reinterpret_cast<const float4*>(&bias[cl * 8]);
        const float4 b1 = *reinterpret_cast<const float4*>(&bias[cl * 8 + 4]);
        float4 o0 = make_float4(acc[0] + b0.x, acc[1] + b0.y, acc[2] + b0.z, acc[3] + b0.w);
        float4 o1 = make_float4(acc[4] + b1.x, acc[5] + b1.y, acc[6] + b1.z, acc[7] + b1.w);
        *reinterpret_cast<float4*>(&out[(size_t)n * C_FEATS + cl * 8]) = o0;
        *reinterpret_cast<float4*>(&out[(size_t)n * C_FEATS + cl * 8 + 4]) = o1;
    }
}

extern "C" void kernel_launch(void* const* d_in, const int* in_sizes, int n_in,
                              void* d_out, int out_size, void* d_ws, size_t ws_size,
                              hipStream_t stream) {
    const float* feat = (const float*)d_in[0];
    const float* W    = (const float*)d_in[1];
    const float* aw   = (const float*)d_in[2];
    const float* bias = (const float*)d_in[3];
    const int*   src  = (const int*)d_in[4];
    const int*   dst  = (const int*)d_in[5];
    float* out = (float*)d_out;

    const int N = in_sizes[0] / C_FEATS;
    const int E = in_sizes[4];
    const int NB = (N + 255) / 256;   // <= 256 blocks for k_scanb (N=50000 -> 196)

    char* p = (char*)d_ws;
    auto take = [&](size_t bytes) {
        char* q = p;
        p += (bytes + 255) & ~size_t(255);
        return q;
    };
    unsigned short* h16 = (unsigned short*)take((size_t)N * C_FEATS * 2);
    float* es      = (float*)take((size_t)N * H_HEADS * 4);
    float* edt     = (float*)take((size_t)N * H_HEADS * 4);
    int*   deg     = (int*)take((size_t)N * 4);
    int*   offs    = (int*)take((size_t)(N + 1) * 4);
    int*   cursor  = (int*)take((size_t)N * 4);
    int*   bsum    = (int*)take((size_t)NB * 4);
    int*   bpre    = (int*)take((size_t)NB * 4);
    int*   ssorted = (int*)take((size_t)E * 4);
    (void)ws_size;

    hipMemsetAsync(deg, 0, (size_t)N * 4, stream);

    k_gemm<<<(N + 31) / 32, 256, 0, stream>>>(feat, W, aw, h16, es, edt, N);
    k_deg<<<(E + 255) / 256, 256, 0, stream>>>(dst, deg, E);
    k_bsum<<<NB, 256, 0, stream>>>(deg, bsum, N);
    k_scanb<<<1, 256, 0, stream>>>(bsum, bpre, NB, offs, N);
    k_scanc<<<NB, 256, 0, stream>>>(deg, bpre, offs, cursor, N);
    k_scatter<<<(E + 255) / 256, 256, 0, stream>>>(src, dst, cursor, ssorted, E);
    k_agg<<<(N + 3) / 4, 256, 0, stream>>>(h16, es, edt, offs, ssorted, bias, out, N);
}

// Round 6
// 166.749 us; speedup vs baseline: 1.5155x; 1.1243x over previous
//
#include <hip/hip_runtime.h>
#include <hip/hip_bf16.h>

#define H_HEADS 8
#define D_OUT 16
#define C_FEATS 128          // H*D = in-feats = 128
#define NEG_SLOPE 0.2f

typedef __attribute__((ext_vector_type(8))) short short8;
typedef __attribute__((ext_vector_type(4))) float f32x4;

__device__ inline unsigned short f2bf(float f) {
    __hip_bfloat16 b = __float2bfloat16(f);
    return *reinterpret_cast<unsigned short*>(&b);
}
__device__ inline float bf2f(unsigned short u) {
    return __uint_as_float((unsigned)u << 16);
}
__device__ inline float bf_lo(unsigned u) { return __uint_as_float(u << 16); }
__device__ inline float bf_hi(unsigned u) { return __uint_as_float(u & 0xffff0000u); }

// ---------------- prologue: W -> split-bf16 fragment layout; zero deg -------
// Fragment layout: Wf[((kc*8 + nt)*64 + lane)*8 + i] = bf16(W[k][col]),
//   k = kc*32 + (lane>>4)*8 + i, col = nt*16 + (lane&15).
// Same k-map is used for the A operand, so the contraction is layout-safe.
__global__ __launch_bounds__(256) void k_prep(const float* __restrict__ W,
                                              unsigned short* __restrict__ Wfh,
                                              unsigned short* __restrict__ Wfl,
                                              int* __restrict__ deg, int N) {
    const int b = blockIdx.x, t = threadIdx.x;
    if (b < 8) {
        const int idx = b * 256 + t;          // 0..2047 = 32 frags x 64 lanes
        const int frag = idx >> 6, lane = idx & 63;
        const int kc = frag >> 3, nt = frag & 7;
        const int kb = kc * 32 + ((lane >> 4) << 3);
        const int col = nt * 16 + (lane & 15);
        unsigned short hs[8], ls[8];
#pragma unroll
        for (int i = 0; i < 8; ++i) {
            const float x = W[(size_t)(kb + i) * C_FEATS + col];
            const unsigned short hh = f2bf(x);
            hs[i] = hh;
            ls[i] = f2bf(x - bf2f(hh));
        }
        uint4 uh, ul;
        uh.x = hs[0] | ((unsigned)hs[1] << 16);
        uh.y = hs[2] | ((unsigned)hs[3] << 16);
        uh.z = hs[4] | ((unsigned)hs[5] << 16);
        uh.w = hs[6] | ((unsigned)hs[7] << 16);
        ul.x = ls[0] | ((unsigned)ls[1] << 16);
        ul.y = ls[2] | ((unsigned)ls[3] << 16);
        ul.z = ls[4] | ((unsigned)ls[5] << 16);
        ul.w = ls[6] | ((unsigned)ls[7] << 16);
        *reinterpret_cast<uint4*>(&Wfh[(size_t)idx * 8]) = uh;
        *reinterpret_cast<uint4*>(&Wfl[(size_t)idx * 8]) = ul;
    } else {
        const int i = (b - 8) * 256 + t;
        if (i < N) deg[i] = 0;
    }
}

// ---------------- MFMA GEMM (+ fused degree count in extra blocks) ---------
// Gemm: block = 4 waves, 64 rows; wave = 16 rows x 128 cols.
// Split precision: h = fh*Wh + fl*Wh + fh*Wl (~f32 accuracy from bf16 MFMA).
__global__ __launch_bounds__(256) void k_gemm_deg(
    const float* __restrict__ feat, const unsigned short* __restrict__ Wfh,
    const unsigned short* __restrict__ Wfl, const int* __restrict__ dst,
    int* __restrict__ deg, unsigned short* __restrict__ h16,
    int N, int E, int degBlocks) {
    const int t = threadIdx.x;
    if ((int)blockIdx.x < degBlocks) {
        const int stride = degBlocks * 256;
        for (int e = blockIdx.x * 256 + t; e < E; e += stride)
            atomicAdd(&deg[dst[e]], 1);
        return;
    }
    const int bid = blockIdx.x - degBlocks;
    const int w = t >> 6, lane = t & 63;
    const int rbase = bid * 64 + w * 16;
    const int rowA = rbase + (lane & 15);
    const int ko = (lane >> 4) << 3;
    const bool rv = rowA < N;
    const float* fr = feat + (size_t)rowA * C_FEATS;

    f32x4 acc[8];
#pragma unroll
    for (int nt = 0; nt < 8; ++nt)
#pragma unroll
        for (int j = 0; j < 4; ++j) acc[nt][j] = 0.f;

#pragma unroll
    for (int kc = 0; kc < 4; ++kc) {
        float4 x0 = make_float4(0.f, 0.f, 0.f, 0.f), x1 = x0;
        if (rv) {
            x0 = *reinterpret_cast<const float4*>(fr + kc * 32 + ko);
            x1 = *reinterpret_cast<const float4*>(fr + kc * 32 + ko + 4);
        }
        const float xs[8] = {x0.x, x0.y, x0.z, x0.w, x1.x, x1.y, x1.z, x1.w};
        short8 ah, al;
#pragma unroll
        for (int i = 0; i < 8; ++i) {
            const unsigned short hh = f2bf(xs[i]);
            ah[i] = (short)hh;
            al[i] = (short)f2bf(xs[i] - bf2f(hh));
        }
#pragma unroll
        for (int nt = 0; nt < 8; ++nt) {
            const size_t off = (((size_t)(kc * 8 + nt)) * 64 + lane) * 8;
            const short8 bh = *reinterpret_cast<const short8*>(Wfh + off);
            const short8 bl = *reinterpret_cast<const short8*>(Wfl + off);
            acc[nt] = __builtin_amdgcn_mfma_f32_16x16x32_bf16(ah, bh, acc[nt], 0, 0, 0);
            acc[nt] = __builtin_amdgcn_mfma_f32_16x16x32_bf16(al, bh, acc[nt], 0, 0, 0);
            acc[nt] = __builtin_amdgcn_mfma_f32_16x16x32_bf16(ah, bl, acc[nt], 0, 0, 0);
        }
    }
    // C layout (verified): col = lane&15, row = (lane>>4)*4 + reg
    const int r0 = rbase + ((lane >> 4) << 2);
    const int colc = lane & 15;
#pragma unroll
    for (int nt = 0; nt < 8; ++nt) {
#pragma unroll
        for (int r = 0; r < 4; ++r) {
            const int row = r0 + r;
            if (row < N)
                h16[(size_t)row * C_FEATS + nt * 16 + colc] = f2bf(acc[nt][r]);
        }
    }
}

// ---------------- logits (from h16) + bsum fused ----------------
__global__ __launch_bounds__(256) void k_logits_bsum(
    const unsigned short* __restrict__ h16, const float* __restrict__ aw,
    float* __restrict__ es, float* __restrict__ ed,
    const int* __restrict__ deg, int* __restrict__ bsum, int N, int LB) {
    const int t = threadIdx.x;
    if ((int)blockIdx.x < LB) {
        const int idx = blockIdx.x * 256 + t;
        if (idx >= N * H_HEADS) return;
        const int n = idx >> 3, hh = idx & 7;
        const uint4 u0 = *reinterpret_cast<const uint4*>(&h16[(size_t)n * C_FEATS + hh * 16]);
        const uint4 u1 = *reinterpret_cast<const uint4*>(&h16[(size_t)n * C_FEATS + hh * 16 + 8]);
        float hv[16];
        hv[0] = bf_lo(u0.x);  hv[1] = bf_hi(u0.x);
        hv[2] = bf_lo(u0.y);  hv[3] = bf_hi(u0.y);
        hv[4] = bf_lo(u0.z);  hv[5] = bf_hi(u0.z);
        hv[6] = bf_lo(u0.w);  hv[7] = bf_hi(u0.w);
        hv[8] = bf_lo(u1.x);  hv[9] = bf_hi(u1.x);
        hv[10] = bf_lo(u1.y); hv[11] = bf_hi(u1.y);
        hv[12] = bf_lo(u1.z); hv[13] = bf_hi(u1.z);
        hv[14] = bf_lo(u1.w); hv[15] = bf_hi(u1.w);
        float s0 = 0.f, s1 = 0.f;
#pragma unroll
        for (int j = 0; j < 16; ++j) {
            s0 = fmaf(hv[j], aw[hh * 16 + j], s0);
            s1 = fmaf(hv[j], aw[C_FEATS + hh * 16 + j], s1);
        }
        es[idx] = s0;
        ed[idx] = s1;
    } else {
        const int i = (blockIdx.x - LB) * 256 + t;
        int v = (i < N) ? deg[i] : 0;
#pragma unroll
        for (int m = 1; m < 64; m <<= 1) v += __shfl_xor(v, m, 64);
        __shared__ int ws[4];
        if ((t & 63) == 0) ws[t >> 6] = v;
        __syncthreads();
        if (t == 0) bsum[blockIdx.x - LB] = ws[0] + ws[1] + ws[2] + ws[3];
    }
}

// ---------------- scan helpers ----------------
__device__ inline int block_scan_incl(int v) {
    int lane = threadIdx.x & 63, w = threadIdx.x >> 6;
    int x = v;
#pragma unroll
    for (int d = 1; d < 64; d <<= 1) {
        int u = __shfl_up(x, d, 64);
        if (lane >= d) x += u;
    }
    __shared__ int wsum[4];
    if (lane == 63) wsum[w] = x;
    __syncthreads();
    int add = 0;
    for (int k = 0; k < w; ++k) add += wsum[k];
    return x + add;
}

__global__ void k_scanb(const int* __restrict__ bsum, int* __restrict__ bpre,
                        int NB, int* __restrict__ offs, int N) {
    int t = threadIdx.x;
    int v = (t < NB) ? bsum[t] : 0;
    int incl = block_scan_incl(v);
    if (t < NB) bpre[t] = incl - v;
    if (t == NB - 1) offs[N] = incl;
}

__global__ void k_scanc(const int* __restrict__ deg, const int* __restrict__ bpre,
                        int* __restrict__ offs, int* __restrict__ cursor, int N) {
    int i = blockIdx.x * 256 + threadIdx.x;
    int v = (i < N) ? deg[i] : 0;
    int incl = block_scan_incl(v);
    int excl = incl - v + bpre[blockIdx.x];
    if (i < N) { offs[i] = excl; cursor[i] = excl; }
}

__global__ void k_scatter(const int* __restrict__ src, const int* __restrict__ dst,
                          int* __restrict__ cursor, int* __restrict__ ssorted, int E) {
    int e = blockIdx.x * 256 + threadIdx.x;
    if (e < E) {
        int d = dst[e];
        int pos = atomicAdd(&cursor[d], 1);
        ssorted[pos] = src[e];
    }
}

// ---------------- two-pass softmax + aggregation (R5-proven, untouched) -----
__global__ __launch_bounds__(256) void k_agg(const unsigned short* __restrict__ h16,
                                             const float* __restrict__ es,
                                             const float* __restrict__ ed,
                                             const int* __restrict__ offs,
                                             const int* __restrict__ ssorted,
                                             const float* __restrict__ bias,
                                             float* __restrict__ out, int N) {
    const int wid = threadIdx.x >> 6, lane = threadIdx.x & 63;
    const int n = blockIdx.x * 4 + wid;
    if (n >= N) return;
    const int beg = offs[n];
    const int deg = offs[n + 1] - beg;

    const int hh = lane >> 3, j0 = lane & 7;
    const float edv = ed[(size_t)n * H_HEADS + hh];

    // ---- Phase A: online softmax stats per head ----
    float m = -1e30f, s = 0.f;
    for (int e = j0; e < deg; e += 8) {
        int sn = ssorted[beg + e];
        float ev = es[(size_t)sn * H_HEADS + hh] + edv;
        ev = ev > 0.f ? ev : NEG_SLOPE * ev;
        if (ev > m) {
            s = s * __expf(m - ev) + 1.f;
            m = ev;
        } else {
            s += __expf(ev - m);
        }
    }
#pragma unroll
    for (int msk = 1; msk < 8; msk <<= 1) {
        float mo = __shfl_xor(m, msk, 64);
        float so = __shfl_xor(s, msk, 64);
        float mn = fmaxf(m, mo);
        s = s * __expf(m - mn) + so * __expf(mo - mn);
        m = mn;
    }
    const float inv = (s > 0.f) ? 1.f / s : 0.f;

    // ---- Phase B ----
    const int cl = lane & 15, q = lane >> 4;
    const int ah = cl >> 1;             // head owning this lane's 8 columns
    const int ab = ah << 3;             // softmax-layout base lane for head ah
    float acc[8];
#pragma unroll
    for (int k = 0; k < 8; ++k) acc[k] = 0.f;

    for (int cb = 0; cb < deg; cb += 8) {
        const int j = cb + j0;
        int sn = 0;
        float alpha = 0.f;
        if (j < deg) {
            sn = ssorted[beg + j];
            float t = es[(size_t)sn * H_HEADS + hh] + edv;
            t = t > 0.f ? t : NEG_SLOPE * t;
            alpha = __expf(t - m) * inv;    // final normalized weight
        }
        int rem = deg - cb; if (rem > 8) rem = 8;
#pragma unroll
        for (int e4 = 0; e4 < 2; ++e4) {
            if (4 * e4 >= rem) break;       // uniform exit
            const int s0 = __shfl(sn, 4 * e4 + 0, 64);
            const int s1 = __shfl(sn, 4 * e4 + 1, 64);
            const int s2 = __shfl(sn, 4 * e4 + 2, 64);
            const int s3 = __shfl(sn, 4 * e4 + 3, 64);
            const int snq = (q == 0) ? s0 : (q == 1) ? s1 : (q == 2) ? s2 : s3;
            const float al = __shfl(alpha, ab + 4 * e4 + q, 64); // 0 for OOB tail
            const uint4 hv = *reinterpret_cast<const uint4*>(
                &h16[(size_t)snq * C_FEATS + cl * 8]);
            acc[0] = fmaf(al, bf_lo(hv.x), acc[0]);
            acc[1] = fmaf(al, bf_hi(hv.x), acc[1]);
            acc[2] = fmaf(al, bf_lo(hv.y), acc[2]);
            acc[3] = fmaf(al, bf_hi(hv.y), acc[3]);
            acc[4] = fmaf(al, bf_lo(hv.z), acc[4]);
            acc[5] = fmaf(al, bf_hi(hv.z), acc[5]);
            acc[6] = fmaf(al, bf_lo(hv.w), acc[6]);
            acc[7] = fmaf(al, bf_hi(hv.w), acc[7]);
        }
    }
#pragma unroll
    for (int k = 0; k < 8; ++k) {
        acc[k] += __shfl_xor(acc[k], 16, 64);
        acc[k] += __shfl_xor(acc[k], 32, 64);
    }
    if (q == 0) {
        const float4 b0 = *reinterpret_cast<const float4*>(&bias[cl * 8]);
        const float4 b1 = *reinterpret_cast<const float4*>(&bias[cl * 8 + 4]);
        float4 o0 = make_float4(acc[0] + b0.x, acc[1] + b0.y, acc[2] + b0.z, acc[3] + b0.w);
        float4 o1 = make_float4(acc[4] + b1.x, acc[5] + b1.y, acc[6] + b1.z, acc[7] + b1.w);
        *reinterpret_cast<float4*>(&out[(size_t)n * C_FEATS + cl * 8]) = o0;
        *reinterpret_cast<float4*>(&out[(size_t)n * C_FEATS + cl * 8 + 4]) = o1;
    }
}

extern "C" void kernel_launch(void* const* d_in, const int* in_sizes, int n_in,
                              void* d_out, int out_size, void* d_ws, size_t ws_size,
                              hipStream_t stream) {
    const float* feat = (const float*)d_in[0];
    const float* W    = (const float*)d_in[1];
    const float* aw   = (const float*)d_in[2];
    const float* bias = (const float*)d_in[3];
    const int*   src  = (const int*)d_in[4];
    const int*   dst  = (const int*)d_in[5];
    float* out = (float*)d_out;

    const int N = in_sizes[0] / C_FEATS;
    const int E = in_sizes[4];
    const int NB = (N + 255) / 256;          // 196 (<= 256 for k_scanb)
    const int GB = (N + 63) / 64;            // gemm blocks (782)
    const int DB = 512;                      // degree-count blocks
    const int LB = (N * H_HEADS + 255) / 256;// logits blocks (1563)

    char* p = (char*)d_ws;
    auto take = [&](size_t bytes) {
        char* q = p;
        p += (bytes + 255) & ~size_t(255);
        return q;
    };
    unsigned short* h16 = (unsigned short*)take((size_t)N * C_FEATS * 2);
    float* es      = (float*)take((size_t)N * H_HEADS * 4);
    float* edt     = (float*)take((size_t)N * H_HEADS * 4);
    int*   deg     = (int*)take((size_t)N * 4);
    int*   offs    = (int*)take((size_t)(N + 1) * 4);
    int*   cursor  = (int*)take((size_t)N * 4);
    int*   bsum    = (int*)take((size_t)NB * 4);
    int*   bpre    = (int*)take((size_t)NB * 4);
    int*   ssorted = (int*)take((size_t)E * 4);
    unsigned short* Wfh = (unsigned short*)take((size_t)C_FEATS * C_FEATS * 2);
    unsigned short* Wfl = (unsigned short*)take((size_t)C_FEATS * C_FEATS * 2);
    (void)ws_size;

    k_prep<<<8 + NB, 256, 0, stream>>>(W, Wfh, Wfl, deg, N);
    k_gemm_deg<<<DB + GB, 256, 0, stream>>>(feat, Wfh, Wfl, dst, deg, h16, N, E, DB);
    k_logits_bsum<<<LB + NB, 256, 0, stream>>>(h16, aw, es, edt, deg, bsum, N, LB);
    k_scanb<<<1, 256, 0, stream>>>(bsum, bpre, NB, offs, N);
    k_scanc<<<NB, 256, 0, stream>>>(deg, bpre, offs, cursor, N);
    k_scatter<<<(E + 255) / 256, 256, 0, stream>>>(src, dst, cursor, ssorted, E);
    k_agg<<<(N + 3) / 4, 256, 0, stream>>>(h16, es, edt, offs, ssorted, bias, out, N);
}

// Round 8
// 157.098 us; speedup vs baseline: 1.6086x; 1.0614x over previous
//
#include <hip/hip_runtime.h>
#include <hip/hip_bf16.h>

#define H_HEADS 8
#define D_OUT 16
#define C_FEATS 128          // H*D = in-feats = 128
#define NEG_SLOPE 0.2f

typedef __attribute__((ext_vector_type(8))) short short8;
typedef __attribute__((ext_vector_type(4))) float f32x4;

__device__ inline unsigned short f2bf(float f) {
    __hip_bfloat16 b = __float2bfloat16(f);
    return *reinterpret_cast<unsigned short*>(&b);
}
__device__ inline float bf2f(unsigned short u) {
    return __uint_as_float((unsigned)u << 16);
}
__device__ inline float bf_lo(unsigned u) { return __uint_as_float(u << 16); }
__device__ inline float bf_hi(unsigned u) { return __uint_as_float(u & 0xffff0000u); }

// ---------------- prologue: W -> split-bf16 fragment layout; zero deg -------
__global__ __launch_bounds__(256) void k_prep(const float* __restrict__ W,
                                              unsigned short* __restrict__ Wfh,
                                              unsigned short* __restrict__ Wfl,
                                              int* __restrict__ deg, int N) {
    const int b = blockIdx.x, t = threadIdx.x;
    if (b < 8) {
        const int idx = b * 256 + t;          // 0..2047 = 32 frags x 64 lanes
        const int frag = idx >> 6, lane = idx & 63;
        const int kc = frag >> 3, nt = frag & 7;
        const int kb = kc * 32 + ((lane >> 4) << 3);
        const int col = nt * 16 + (lane & 15);
        unsigned short hs[8], ls[8];
#pragma unroll
        for (int i = 0; i < 8; ++i) {
            const float x = W[(size_t)(kb + i) * C_FEATS + col];
            const unsigned short hh = f2bf(x);
            hs[i] = hh;
            ls[i] = f2bf(x - bf2f(hh));
        }
        uint4 uh, ul;
        uh.x = hs[0] | ((unsigned)hs[1] << 16);
        uh.y = hs[2] | ((unsigned)hs[3] << 16);
        uh.z = hs[4] | ((unsigned)hs[5] << 16);
        uh.w = hs[6] | ((unsigned)hs[7] << 16);
        ul.x = ls[0] | ((unsigned)ls[1] << 16);
        ul.y = ls[2] | ((unsigned)ls[3] << 16);
        ul.z = ls[4] | ((unsigned)ls[5] << 16);
        ul.w = ls[6] | ((unsigned)ls[7] << 16);
        *reinterpret_cast<uint4*>(&Wfh[(size_t)idx * 8]) = uh;
        *reinterpret_cast<uint4*>(&Wfl[(size_t)idx * 8]) = ul;
    } else {
        const int i = (b - 8) * 256 + t;
        if (i < N) deg[i] = 0;
    }
}

// ---------------- MFMA GEMM (+ fused degree count in extra blocks) ---------
__global__ __launch_bounds__(256) void k_gemm_deg(
    const float* __restrict__ feat, const unsigned short* __restrict__ Wfh,
    const unsigned short* __restrict__ Wfl, const int* __restrict__ dst,
    int* __restrict__ deg, unsigned short* __restrict__ h16,
    int N, int E, int degBlocks) {
    const int t = threadIdx.x;
    if ((int)blockIdx.x < degBlocks) {
        const int stride = degBlocks * 256;
        for (int e = blockIdx.x * 256 + t; e < E; e += stride)
            atomicAdd(&deg[dst[e]], 1);
        return;
    }
    const int bid = blockIdx.x - degBlocks;
    const int w = t >> 6, lane = t & 63;
    const int rbase = bid * 64 + w * 16;
    const int rowA = rbase + (lane & 15);
    const int ko = (lane >> 4) << 3;
    const bool rv = rowA < N;
    const float* fr = feat + (size_t)rowA * C_FEATS;

    f32x4 acc[8];
#pragma unroll
    for (int nt = 0; nt < 8; ++nt)
#pragma unroll
        for (int j = 0; j < 4; ++j) acc[nt][j] = 0.f;

#pragma unroll
    for (int kc = 0; kc < 4; ++kc) {
        float4 x0 = make_float4(0.f, 0.f, 0.f, 0.f), x1 = x0;
        if (rv) {
            x0 = *reinterpret_cast<const float4*>(fr + kc * 32 + ko);
            x1 = *reinterpret_cast<const float4*>(fr + kc * 32 + ko + 4);
        }
        const float xs[8] = {x0.x, x0.y, x0.z, x0.w, x1.x, x1.y, x1.z, x1.w};
        short8 ah, al;
#pragma unroll
        for (int i = 0; i < 8; ++i) {
            const unsigned short hh = f2bf(xs[i]);
            ah[i] = (short)hh;
            al[i] = (short)f2bf(xs[i] - bf2f(hh));
        }
#pragma unroll
        for (int nt = 0; nt < 8; ++nt) {
            const size_t off = (((size_t)(kc * 8 + nt)) * 64 + lane) * 8;
            const short8 bh = *reinterpret_cast<const short8*>(Wfh + off);
            const short8 bl = *reinterpret_cast<const short8*>(Wfl + off);
            acc[nt] = __builtin_amdgcn_mfma_f32_16x16x32_bf16(ah, bh, acc[nt], 0, 0, 0);
            acc[nt] = __builtin_amdgcn_mfma_f32_16x16x32_bf16(al, bh, acc[nt], 0, 0, 0);
            acc[nt] = __builtin_amdgcn_mfma_f32_16x16x32_bf16(ah, bl, acc[nt], 0, 0, 0);
        }
    }
    // C layout (verified): col = lane&15, row = (lane>>4)*4 + reg
    const int r0 = rbase + ((lane >> 4) << 2);
    const int colc = lane & 15;
#pragma unroll
    for (int nt = 0; nt < 8; ++nt) {
#pragma unroll
        for (int r = 0; r < 4; ++r) {
            const int row = r0 + r;
            if (row < N)
                h16[(size_t)row * C_FEATS + nt * 16 + colc] = f2bf(acc[nt][r]);
        }
    }
}

// ---------------- logits (from h16) + bsum fused ----------------
__global__ __launch_bounds__(256) void k_logits_bsum(
    const unsigned short* __restrict__ h16, const float* __restrict__ aw,
    float* __restrict__ es, float* __restrict__ ed,
    const int* __restrict__ deg, int* __restrict__ bsum, int N, int LB) {
    const int t = threadIdx.x;
    if ((int)blockIdx.x < LB) {
        const int idx = blockIdx.x * 256 + t;
        if (idx >= N * H_HEADS) return;
        const int n = idx >> 3, hh = idx & 7;
        const uint4 u0 = *reinterpret_cast<const uint4*>(&h16[(size_t)n * C_FEATS + hh * 16]);
        const uint4 u1 = *reinterpret_cast<const uint4*>(&h16[(size_t)n * C_FEATS + hh * 16 + 8]);
        float hv[16];
        hv[0] = bf_lo(u0.x);  hv[1] = bf_hi(u0.x);
        hv[2] = bf_lo(u0.y);  hv[3] = bf_hi(u0.y);
        hv[4] = bf_lo(u0.z);  hv[5] = bf_hi(u0.z);
        hv[6] = bf_lo(u0.w);  hv[7] = bf_hi(u0.w);
        hv[8] = bf_lo(u1.x);  hv[9] = bf_hi(u1.x);
        hv[10] = bf_lo(u1.y); hv[11] = bf_hi(u1.y);
        hv[12] = bf_lo(u1.z); hv[13] = bf_hi(u1.z);
        hv[14] = bf_lo(u1.w); hv[15] = bf_hi(u1.w);
        float s0 = 0.f, s1 = 0.f;
#pragma unroll
        for (int j = 0; j < 16; ++j) {
            s0 = fmaf(hv[j], aw[hh * 16 + j], s0);
            s1 = fmaf(hv[j], aw[C_FEATS + hh * 16 + j], s1);
        }
        es[idx] = s0;
        ed[idx] = s1;
    } else {
        const int i = (blockIdx.x - LB) * 256 + t;
        int v = (i < N) ? deg[i] : 0;
#pragma unroll
        for (int m = 1; m < 64; m <<= 1) v += __shfl_xor(v, m, 64);
        __shared__ int ws[4];
        if ((t & 63) == 0) ws[t >> 6] = v;
        __syncthreads();
        if (t == 0) bsum[blockIdx.x - LB] = ws[0] + ws[1] + ws[2] + ws[3];
    }
}

// ---------------- scan helpers ----------------
__device__ inline int block_scan_incl(int v) {
    int lane = threadIdx.x & 63, w = threadIdx.x >> 6;
    int x = v;
#pragma unroll
    for (int d = 1; d < 64; d <<= 1) {
        int u = __shfl_up(x, d, 64);
        if (lane >= d) x += u;
    }
    __shared__ int wsum[4];
    if (lane == 63) wsum[w] = x;
    __syncthreads();
    int add = 0;
    for (int k = 0; k < w; ++k) add += wsum[k];
    return x + add;
}

__global__ void k_scanb(const int* __restrict__ bsum, int* __restrict__ bpre,
                        int NB, int* __restrict__ offs, int N) {
    int t = threadIdx.x;
    int v = (t < NB) ? bsum[t] : 0;
    int incl = block_scan_incl(v);
    if (t < NB) bpre[t] = incl - v;
    if (t == NB - 1) offs[N] = incl;
}

__global__ void k_scanc(const int* __restrict__ deg, const int* __restrict__ bpre,
                        int* __restrict__ offs, int* __restrict__ cursor, int N) {
    int i = blockIdx.x * 256 + threadIdx.x;
    int v = (i < N) ? deg[i] : 0;
    int incl = block_scan_incl(v);
    int excl = incl - v + bpre[blockIdx.x];
    if (i < N) { offs[i] = excl; cursor[i] = excl; }
}

__global__ void k_scatter(const int* __restrict__ src, const int* __restrict__ dst,
                          int* __restrict__ cursor, int* __restrict__ ssorted, int E) {
    int e = blockIdx.x * 256 + threadIdx.x;
    if (e < E) {
        int d = dst[e];
        int pos = atomicAdd(&cursor[d], 1);
        ssorted[pos] = src[e];
    }
}

// ---------------- two-pass softmax + aggregation ----------------
// One wave per node. deg<=32 fast path: sn/ev register-cached across phases
// (4 chunks, fully unrolled -> static indexing, stays in VGPRs). deg>32:
// R5-proven streaming fallback. Both: phase A online (m,s) in softmax layout
// (lane = hh*8 + j0); phase B alpha via shfl from softmax layout, gather
// cl = lane&15 owns 8 bf16 cols (uint4 16B), q = lane>>4 -> 4 edges parallel.
__global__ __launch_bounds__(256) void k_agg(const unsigned short* __restrict__ h16,
                                             const float* __restrict__ es,
                                             const float* __restrict__ ed,
                                             const int* __restrict__ offs,
                                             const int* __restrict__ ssorted,
                                             const float* __restrict__ bias,
                                             float* __restrict__ out, int N) {
    const int wid = threadIdx.x >> 6, lane = threadIdx.x & 63;
    const int n = blockIdx.x * 4 + wid;
    if (n >= N) return;
    const int beg = offs[n];
    const int deg = offs[n + 1] - beg;

    const int hh = lane >> 3, j0 = lane & 7;
    const float edv = ed[(size_t)n * H_HEADS + hh];

    const int cl = lane & 15, q = lane >> 4;
    const int ah = cl >> 1;             // head owning this lane's 8 columns
    const int ab = ah << 3;             // softmax-layout base lane for head ah
    float acc[8];
#pragma unroll
    for (int k = 0; k < 8; ++k) acc[k] = 0.f;

    float m = -1e30f, s = 0.f;

    if (deg <= 32) {
        // ---------- cached fast path ----------
        int snc[4];
        float evc[4];
#pragma unroll
        for (int c = 0; c < 4; ++c) {
            const int j = c * 8 + j0;
            const bool va = (j < deg);
            int sn = 0;
            float ev = -1e30f;
            if (va) {
                sn = ssorted[beg + j];
                float t = es[(size_t)sn * H_HEADS + hh] + edv;
                ev = t > 0.f ? t : NEG_SLOPE * t;
                if (ev > m) {
                    s = s * __expf(m - ev) + 1.f;
                    m = ev;
                } else {
                    s += __expf(ev - m);
                }
            }
            snc[c] = sn;
            evc[c] = ev;
        }
#pragma unroll
        for (int msk = 1; msk < 8; msk <<= 1) {
            float mo = __shfl_xor(m, msk, 64);
            float so = __shfl_xor(s, msk, 64);
            float mn = fmaxf(m, mo);
            s = s * __expf(m - mn) + so * __expf(mo - mn);
            m = mn;
        }
        const float inv = (s > 0.f) ? 1.f / s : 0.f;

#pragma unroll
        for (int c = 0; c < 4; ++c) {
            const int cb = c * 8;
            if (cb >= deg) break;                 // wave-uniform exit
            const float alpha = (cb + j0 < deg) ? __expf(evc[c] - m) * inv : 0.f;
            const int sn = snc[c];
            int rem = deg - cb; if (rem > 8) rem = 8;
#pragma unroll
            for (int e4 = 0; e4 < 2; ++e4) {
                if (4 * e4 >= rem) break;         // wave-uniform exit
                const int s0 = __shfl(sn, 4 * e4 + 0, 64);
                const int s1 = __shfl(sn, 4 * e4 + 1, 64);
                const int s2 = __shfl(sn, 4 * e4 + 2, 64);
                const int s3 = __shfl(sn, 4 * e4 + 3, 64);
                const int snq = (q == 0) ? s0 : (q == 1) ? s1 : (q == 2) ? s2 : s3;
                const float al = __shfl(alpha, ab + 4 * e4 + q, 64);
                const uint4 hv = *reinterpret_cast<const uint4*>(
                    &h16[(size_t)snq * C_FEATS + cl * 8]);
                acc[0] = fmaf(al, bf_lo(hv.x), acc[0]);
                acc[1] = fmaf(al, bf_hi(hv.x), acc[1]);
                acc[2] = fmaf(al, bf_lo(hv.y), acc[2]);
                acc[3] = fmaf(al, bf_hi(hv.y), acc[3]);
                acc[4] = fmaf(al, bf_lo(hv.z), acc[4]);
                acc[5] = fmaf(al, bf_hi(hv.z), acc[5]);
                acc[6] = fmaf(al, bf_lo(hv.w), acc[6]);
                acc[7] = fmaf(al, bf_hi(hv.w), acc[7]);
            }
        }
    } else {
        // ---------- streaming fallback (R5-proven) ----------
        for (int e = j0; e < deg; e += 8) {
            int sn = ssorted[beg + e];
            float ev = es[(size_t)sn * H_HEADS + hh] + edv;
            ev = ev > 0.f ? ev : NEG_SLOPE * ev;
            if (ev > m) {
                s = s * __expf(m - ev) + 1.f;
                m = ev;
            } else {
                s += __expf(ev - m);
            }
        }
#pragma unroll
        for (int msk = 1; msk < 8; msk <<= 1) {
            float mo = __shfl_xor(m, msk, 64);
            float so = __shfl_xor(s, msk, 64);
            float mn = fmaxf(m, mo);
            s = s * __expf(m - mn) + so * __expf(mo - mn);
            m = mn;
        }
        const float inv = (s > 0.f) ? 1.f / s : 0.f;

        for (int cb = 0; cb < deg; cb += 8) {
            const int j = cb + j0;
            int sn = 0;
            float alpha = 0.f;
            if (j < deg) {
                sn = ssorted[beg + j];
                float t = es[(size_t)sn * H_HEADS + hh] + edv;
                t = t > 0.f ? t : NEG_SLOPE * t;
                alpha = __expf(t - m) * inv;
            }
            int rem = deg - cb; if (rem > 8) rem = 8;
#pragma unroll
            for (int e4 = 0; e4 < 2; ++e4) {
                if (4 * e4 >= rem) break;
                const int s0 = __shfl(sn, 4 * e4 + 0, 64);
                const int s1 = __shfl(sn, 4 * e4 + 1, 64);
                const int s2 = __shfl(sn, 4 * e4 + 2, 64);
                const int s3 = __shfl(sn, 4 * e4 + 3, 64);
                const int snq = (q == 0) ? s0 : (q == 1) ? s1 : (q == 2) ? s2 : s3;
                const float al = __shfl(alpha, ab + 4 * e4 + q, 64);
                const uint4 hv = *reinterpret_cast<const uint4*>(
                    &h16[(size_t)snq * C_FEATS + cl * 8]);
                acc[0] = fmaf(al, bf_lo(hv.x), acc[0]);
                acc[1] = fmaf(al, bf_hi(hv.x), acc[1]);
                acc[2] = fmaf(al, bf_lo(hv.y), acc[2]);
                acc[3] = fmaf(al, bf_hi(hv.y), acc[3]);
                acc[4] = fmaf(al, bf_lo(hv.z), acc[4]);
                acc[5] = fmaf(al, bf_hi(hv.z), acc[5]);
                acc[6] = fmaf(al, bf_lo(hv.w), acc[6]);
                acc[7] = fmaf(al, bf_hi(hv.w), acc[7]);
            }
        }
    }

#pragma unroll
    for (int k = 0; k < 8; ++k) {
        acc[k] += __shfl_xor(acc[k], 16, 64);
        acc[k] += __shfl_xor(acc[k], 32, 64);
    }
    if (q == 0) {
        const float4 b0 = *reinterpret_cast<const float4*>(&bias[cl * 8]);
        const float4 b1 = *reinterpret_cast<const float4*>(&bias[cl * 8 + 4]);
        float4 o0 = make_float4(acc[0] + b0.x, acc[1] + b0.y, acc[2] + b0.z, acc[3] + b0.w);
        float4 o1 = make_float4(acc[4] + b1.x, acc[5] + b1.y, acc[6] + b1.z, acc[7] + b1.w);
        *reinterpret_cast<float4*>(&out[(size_t)n * C_FEATS + cl * 8]) = o0;
        *reinterpret_cast<float4*>(&out[(size_t)n * C_FEATS + cl * 8 + 4]) = o1;
    }
}

extern "C" void kernel_launch(void* const* d_in, const int* in_sizes, int n_in,
                              void* d_out, int out_size, void* d_ws, size_t ws_size,
                              hipStream_t stream) {
    const float* feat = (const float*)d_in[0];
    const float* W    = (const float*)d_in[1];
    const float* aw   = (const float*)d_in[2];
    const float* bias = (const float*)d_in[3];
    const int*   src  = (const int*)d_in[4];
    const int*   dst  = (const int*)d_in[5];
    float* out = (float*)d_out;

    const int N = in_sizes[0] / C_FEATS;
    const int E = in_sizes[4];
    const int NB = (N + 255) / 256;          // 196 (<= 256 for k_scanb)
    const int GB = (N + 63) / 64;            // gemm blocks (782)
    const int DB = 512;                      // degree-count blocks
    const int LB = (N * H_HEADS + 255) / 256;// logits blocks (1563)

    char* p = (char*)d_ws;
    auto take = [&](size_t bytes) {
        char* q = p;
        p += (bytes + 255) & ~size_t(255);
        return q;
    };
    unsigned short* h16 = (unsigned short*)take((size_t)N * C_FEATS * 2);
    float* es      = (float*)take((size_t)N * H_HEADS * 4);
    float* edt     = (float*)take((size_t)N * H_HEADS * 4);
    int*   deg     = (int*)take((size_t)N * 4);
    int*   offs    = (int*)take((size_t)(N + 1) * 4);
    int*   cursor  = (int*)take((size_t)N * 4);
    int*   bsum    = (int*)take((size_t)NB * 4);
    int*   bpre    = (int*)take((size_t)NB * 4);
    int*   ssorted = (int*)take((size_t)E * 4);
    unsigned short* Wfh = (unsigned short*)take((size_t)C_FEATS * C_FEATS * 2);
    unsigned short* Wfl = (unsigned short*)take((size_t)C_FEATS * C_FEATS * 2);
    (void)ws_size;

    k_prep<<<8 + NB, 256, 0, stream>>>(W, Wfh, Wfl, deg, N);
    k_gemm_deg<<<DB + GB, 256, 0, stream>>>(feat, Wfh, Wfl, dst, deg, h16, N, E, DB);
    k_logits_bsum<<<LB + NB, 256, 0, stream>>>(h16, aw, es, edt, deg, bsum, N, LB);
    k_scanb<<<1, 256, 0, stream>>>(bsum, bpre, NB, offs, N);
    k_scanc<<<NB, 256, 0, stream>>>(deg, bpre, offs, cursor, N);
    k_scatter<<<(E + 255) / 256, 256, 0, stream>>>(src, dst, cursor, ssorted, E);
    k_agg<<<(N + 3) / 4, 256, 0, stream>>>(h16, es, edt, offs, ssorted, bias, out, N);
}

// Round 9
// 150.119 us; speedup vs baseline: 1.6834x; 1.0465x over previous
//
#include <hip/hip_runtime.h>
#include <hip/hip_bf16.h>

#define H_HEADS 8
#define D_OUT 16
#define C_FEATS 128          // H*D = in-feats = 128
#define NEG_SLOPE 0.2f

typedef __attribute__((ext_vector_type(8))) short short8;
typedef __attribute__((ext_vector_type(4))) float f32x4;

__device__ inline unsigned short f2bf(float f) {
    __hip_bfloat16 b = __float2bfloat16(f);
    return *reinterpret_cast<unsigned short*>(&b);
}
__device__ inline float bf2f(unsigned short u) {
    return __uint_as_float((unsigned)u << 16);
}
__device__ inline float bf_lo(unsigned u) { return __uint_as_float(u << 16); }
__device__ inline float bf_hi(unsigned u) { return __uint_as_float(u & 0xffff0000u); }

// ---------------- prologue: W -> split-bf16 fragment layout; zero deg -------
__global__ __launch_bounds__(256) void k_prep(const float* __restrict__ W,
                                              unsigned short* __restrict__ Wfh,
                                              unsigned short* __restrict__ Wfl,
                                              int* __restrict__ deg, int N) {
    const int b = blockIdx.x, t = threadIdx.x;
    if (b < 8) {
        const int idx = b * 256 + t;          // 0..2047 = 32 frags x 64 lanes
        const int frag = idx >> 6, lane = idx & 63;
        const int kc = frag >> 3, nt = frag & 7;
        const int kb = kc * 32 + ((lane >> 4) << 3);
        const int col = nt * 16 + (lane & 15);
        unsigned short hs[8], ls[8];
#pragma unroll
        for (int i = 0; i < 8; ++i) {
            const float x = W[(size_t)(kb + i) * C_FEATS + col];
            const unsigned short hh = f2bf(x);
            hs[i] = hh;
            ls[i] = f2bf(x - bf2f(hh));
        }
        uint4 uh, ul;
        uh.x = hs[0] | ((unsigned)hs[1] << 16);
        uh.y = hs[2] | ((unsigned)hs[3] << 16);
        uh.z = hs[4] | ((unsigned)hs[5] << 16);
        uh.w = hs[6] | ((unsigned)hs[7] << 16);
        ul.x = ls[0] | ((unsigned)ls[1] << 16);
        ul.y = ls[2] | ((unsigned)ls[3] << 16);
        ul.z = ls[4] | ((unsigned)ls[5] << 16);
        ul.w = ls[6] | ((unsigned)ls[7] << 16);
        *reinterpret_cast<uint4*>(&Wfh[(size_t)idx * 8]) = uh;
        *reinterpret_cast<uint4*>(&Wfl[(size_t)idx * 8]) = ul;
    } else {
        const int i = (b - 8) * 256 + t;
        if (i < N) deg[i] = 0;
    }
}

// ---------------- MFMA GEMM, LDS-staged W (+ fused degree count) -----------
// 512 threads = 8 waves, 128 rows/block. Wfh+Wfl (64KB) staged to LDS once
// per block; inner loop reads fragments via ds_read_b128 (no L2 latency
// chain). Wave = 16 rows x 128 cols; 96 MFMA/wave (3-term split-bf16).
__global__ __launch_bounds__(512) void k_gemm_deg(
    const float* __restrict__ feat, const unsigned short* __restrict__ Wfh,
    const unsigned short* __restrict__ Wfl, const int* __restrict__ dst,
    int* __restrict__ deg, unsigned short* __restrict__ h16,
    int N, int E, int degBlocks) {
    const int t = threadIdx.x;
    if ((int)blockIdx.x < degBlocks) {
        const int stride = degBlocks * 512;
        for (int e = blockIdx.x * 512 + t; e < E; e += stride)
            atomicAdd(&deg[dst[e]], 1);
        return;
    }
    __shared__ uint4 sW[4096];                 // [0,2048): Wfh  [2048,4096): Wfl
    {
        const uint4* gh = reinterpret_cast<const uint4*>(Wfh);
        const uint4* gl = reinterpret_cast<const uint4*>(Wfl);
#pragma unroll
        for (int i = 0; i < 4; ++i) {
            const int j = t + i * 512;
            sW[j] = gh[j];
            sW[j + 2048] = gl[j];
        }
    }
    __syncthreads();

    const int bid = blockIdx.x - degBlocks;
    const int w = t >> 6, lane = t & 63;
    const int rbase = bid * 128 + w * 16;
    const int rowA = rbase + (lane & 15);
    const int ko = (lane >> 4) << 3;
    const bool rv = rowA < N;
    const float* fr = feat + (size_t)rowA * C_FEATS;

    f32x4 acc[8];
#pragma unroll
    for (int nt = 0; nt < 8; ++nt)
#pragma unroll
        for (int j = 0; j < 4; ++j) acc[nt][j] = 0.f;

#pragma unroll
    for (int kc = 0; kc < 4; ++kc) {
        float4 x0 = make_float4(0.f, 0.f, 0.f, 0.f), x1 = x0;
        if (rv) {
            x0 = *reinterpret_cast<const float4*>(fr + kc * 32 + ko);
            x1 = *reinterpret_cast<const float4*>(fr + kc * 32 + ko + 4);
        }
        const float xs[8] = {x0.x, x0.y, x0.z, x0.w, x1.x, x1.y, x1.z, x1.w};
        short8 ah, al;
#pragma unroll
        for (int i = 0; i < 8; ++i) {
            const unsigned short hh = f2bf(xs[i]);
            ah[i] = (short)hh;
            al[i] = (short)f2bf(xs[i] - bf2f(hh));
        }
#pragma unroll
        for (int nt = 0; nt < 8; ++nt) {
            const int fi = (kc * 8 + nt) * 64 + lane;
            const short8 bh = *reinterpret_cast<const short8*>(&sW[fi]);
            const short8 bl = *reinterpret_cast<const short8*>(&sW[fi + 2048]);
            acc[nt] = __builtin_amdgcn_mfma_f32_16x16x32_bf16(ah, bh, acc[nt], 0, 0, 0);
            acc[nt] = __builtin_amdgcn_mfma_f32_16x16x32_bf16(al, bh, acc[nt], 0, 0, 0);
            acc[nt] = __builtin_amdgcn_mfma_f32_16x16x32_bf16(ah, bl, acc[nt], 0, 0, 0);
        }
    }
    // C layout (verified): col = lane&15, row = (lane>>4)*4 + reg
    const int r0 = rbase + ((lane >> 4) << 2);
    const int colc = lane & 15;
#pragma unroll
    for (int nt = 0; nt < 8; ++nt) {
#pragma unroll
        for (int r = 0; r < 4; ++r) {
            const int row = r0 + r;
            if (row < N)
                h16[(size_t)row * C_FEATS + nt * 16 + colc] = f2bf(acc[nt][r]);
        }
    }
}

// ---------------- logits (from h16) + bsum fused ----------------
__global__ __launch_bounds__(256) void k_logits_bsum(
    const unsigned short* __restrict__ h16, const float* __restrict__ aw,
    float* __restrict__ es, float* __restrict__ ed,
    const int* __restrict__ deg, int* __restrict__ bsum, int N, int LB) {
    const int t = threadIdx.x;
    if ((int)blockIdx.x < LB) {
        const int idx = blockIdx.x * 256 + t;
        if (idx >= N * H_HEADS) return;
        const int n = idx >> 3, hh = idx & 7;
        const uint4 u0 = *reinterpret_cast<const uint4*>(&h16[(size_t)n * C_FEATS + hh * 16]);
        const uint4 u1 = *reinterpret_cast<const uint4*>(&h16[(size_t)n * C_FEATS + hh * 16 + 8]);
        float hv[16];
        hv[0] = bf_lo(u0.x);  hv[1] = bf_hi(u0.x);
        hv[2] = bf_lo(u0.y);  hv[3] = bf_hi(u0.y);
        hv[4] = bf_lo(u0.z);  hv[5] = bf_hi(u0.z);
        hv[6] = bf_lo(u0.w);  hv[7] = bf_hi(u0.w);
        hv[8] = bf_lo(u1.x);  hv[9] = bf_hi(u1.x);
        hv[10] = bf_lo(u1.y); hv[11] = bf_hi(u1.y);
        hv[12] = bf_lo(u1.z); hv[13] = bf_hi(u1.z);
        hv[14] = bf_lo(u1.w); hv[15] = bf_hi(u1.w);
        float s0 = 0.f, s1 = 0.f;
#pragma unroll
        for (int j = 0; j < 16; ++j) {
            s0 = fmaf(hv[j], aw[hh * 16 + j], s0);
            s1 = fmaf(hv[j], aw[C_FEATS + hh * 16 + j], s1);
        }
        es[idx] = s0;
        ed[idx] = s1;
    } else {
        const int i = (blockIdx.x - LB) * 256 + t;
        int v = (i < N) ? deg[i] : 0;
#pragma unroll
        for (int m = 1; m < 64; m <<= 1) v += __shfl_xor(v, m, 64);
        __shared__ int ws[4];
        if ((t & 63) == 0) ws[t >> 6] = v;
        __syncthreads();
        if (t == 0) bsum[blockIdx.x - LB] = ws[0] + ws[1] + ws[2] + ws[3];
    }
}

// ---------------- scan helpers ----------------
__device__ inline int block_scan_incl(int v) {
    int lane = threadIdx.x & 63, w = threadIdx.x >> 6;
    int x = v;
#pragma unroll
    for (int d = 1; d < 64; d <<= 1) {
        int u = __shfl_up(x, d, 64);
        if (lane >= d) x += u;
    }
    __shared__ int wsum[4];
    if (lane == 63) wsum[w] = x;
    __syncthreads();
    int add = 0;
    for (int k = 0; k < w; ++k) add += wsum[k];
    return x + add;
}

__global__ void k_scanb(const int* __restrict__ bsum, int* __restrict__ bpre,
                        int NB, int* __restrict__ offs, int N) {
    int t = threadIdx.x;
    int v = (t < NB) ? bsum[t] : 0;
    int incl = block_scan_incl(v);
    if (t < NB) bpre[t] = incl - v;
    if (t == NB - 1) offs[N] = incl;
}

__global__ void k_scanc(const int* __restrict__ deg, const int* __restrict__ bpre,
                        int* __restrict__ offs, int* __restrict__ cursor, int N) {
    int i = blockIdx.x * 256 + threadIdx.x;
    int v = (i < N) ? deg[i] : 0;
    int incl = block_scan_incl(v);
    int excl = incl - v + bpre[blockIdx.x];
    if (i < N) { offs[i] = excl; cursor[i] = excl; }
}

__global__ void k_scatter(const int* __restrict__ src, const int* __restrict__ dst,
                          int* __restrict__ cursor, int* __restrict__ ssorted, int E) {
    int e = blockIdx.x * 256 + threadIdx.x;
    if (e < E) {
        int d = dst[e];
        int pos = atomicAdd(&cursor[d], 1);
        ssorted[pos] = src[e];
    }
}

// ---------------- two-pass softmax + aggregation (R8-proven, untouched) -----
__global__ __launch_bounds__(256) void k_agg(const unsigned short* __restrict__ h16,
                                             const float* __restrict__ es,
                                             const float* __restrict__ ed,
                                             const int* __restrict__ offs,
                                             const int* __restrict__ ssorted,
                                             const float* __restrict__ bias,
                                             float* __restrict__ out, int N) {
    const int wid = threadIdx.x >> 6, lane = threadIdx.x & 63;
    const int n = blockIdx.x * 4 + wid;
    if (n >= N) return;
    const int beg = offs[n];
    const int deg = offs[n + 1] - beg;

    const int hh = lane >> 3, j0 = lane & 7;
    const float edv = ed[(size_t)n * H_HEADS + hh];

    const int cl = lane & 15, q = lane >> 4;
    const int ah = cl >> 1;             // head owning this lane's 8 columns
    const int ab = ah << 3;             // softmax-layout base lane for head ah
    float acc[8];
#pragma unroll
    for (int k = 0; k < 8; ++k) acc[k] = 0.f;

    float m = -1e30f, s = 0.f;

    if (deg <= 32) {
        // ---------- cached fast path ----------
        int snc[4];
        float evc[4];
#pragma unroll
        for (int c = 0; c < 4; ++c) {
            const int j = c * 8 + j0;
            const bool va = (j < deg);
            int sn = 0;
            float ev = -1e30f;
            if (va) {
                sn = ssorted[beg + j];
                float t = es[(size_t)sn * H_HEADS + hh] + edv;
                ev = t > 0.f ? t : NEG_SLOPE * t;
                if (ev > m) {
                    s = s * __expf(m - ev) + 1.f;
                    m = ev;
                } else {
                    s += __expf(ev - m);
                }
            }
            snc[c] = sn;
            evc[c] = ev;
        }
#pragma unroll
        for (int msk = 1; msk < 8; msk <<= 1) {
            float mo = __shfl_xor(m, msk, 64);
            float so = __shfl_xor(s, msk, 64);
            float mn = fmaxf(m, mo);
            s = s * __expf(m - mn) + so * __expf(mo - mn);
            m = mn;
        }
        const float inv = (s > 0.f) ? 1.f / s : 0.f;

#pragma unroll
        for (int c = 0; c < 4; ++c) {
            const int cb = c * 8;
            if (cb >= deg) break;                 // wave-uniform exit
            const float alpha = (cb + j0 < deg) ? __expf(evc[c] - m) * inv : 0.f;
            const int sn = snc[c];
            int rem = deg - cb; if (rem > 8) rem = 8;
#pragma unroll
            for (int e4 = 0; e4 < 2; ++e4) {
                if (4 * e4 >= rem) break;         // wave-uniform exit
                const int s0 = __shfl(sn, 4 * e4 + 0, 64);
                const int s1 = __shfl(sn, 4 * e4 + 1, 64);
                const int s2 = __shfl(sn, 4 * e4 + 2, 64);
                const int s3 = __shfl(sn, 4 * e4 + 3, 64);
                const int snq = (q == 0) ? s0 : (q == 1) ? s1 : (q == 2) ? s2 : s3;
                const float al = __shfl(alpha, ab + 4 * e4 + q, 64);
                const uint4 hv = *reinterpret_cast<const uint4*>(
                    &h16[(size_t)snq * C_FEATS + cl * 8]);
                acc[0] = fmaf(al, bf_lo(hv.x), acc[0]);
                acc[1] = fmaf(al, bf_hi(hv.x), acc[1]);
                acc[2] = fmaf(al, bf_lo(hv.y), acc[2]);
                acc[3] = fmaf(al, bf_hi(hv.y), acc[3]);
                acc[4] = fmaf(al, bf_lo(hv.z), acc[4]);
                acc[5] = fmaf(al, bf_hi(hv.z), acc[5]);
                acc[6] = fmaf(al, bf_lo(hv.w), acc[6]);
                acc[7] = fmaf(al, bf_hi(hv.w), acc[7]);
            }
        }
    } else {
        // ---------- streaming fallback ----------
        for (int e = j0; e < deg; e += 8) {
            int sn = ssorted[beg + e];
            float ev = es[(size_t)sn * H_HEADS + hh] + edv;
            ev = ev > 0.f ? ev : NEG_SLOPE * ev;
            if (ev > m) {
                s = s * __expf(m - ev) + 1.f;
                m = ev;
            } else {
                s += __expf(ev - m);
            }
        }
#pragma unroll
        for (int msk = 1; msk < 8; msk <<= 1) {
            float mo = __shfl_xor(m, msk, 64);
            float so = __shfl_xor(s, msk, 64);
            float mn = fmaxf(m, mo);
            s = s * __expf(m - mn) + so * __expf(mo - mn);
            m = mn;
        }
        const float inv = (s > 0.f) ? 1.f / s : 0.f;

        for (int cb = 0; cb < deg; cb += 8) {
            const int j = cb + j0;
            int sn = 0;
            float alpha = 0.f;
            if (j < deg) {
                sn = ssorted[beg + j];
                float t = es[(size_t)sn * H_HEADS + hh] + edv;
                t = t > 0.f ? t : NEG_SLOPE * t;
                alpha = __expf(t - m) * inv;
            }
            int rem = deg - cb; if (rem > 8) rem = 8;
#pragma unroll
            for (int e4 = 0; e4 < 2; ++e4) {
                if (4 * e4 >= rem) break;
                const int s0 = __shfl(sn, 4 * e4 + 0, 64);
                const int s1 = __shfl(sn, 4 * e4 + 1, 64);
                const int s2 = __shfl(sn, 4 * e4 + 2, 64);
                const int s3 = __shfl(sn, 4 * e4 + 3, 64);
                const int snq = (q == 0) ? s0 : (q == 1) ? s1 : (q == 2) ? s2 : s3;
                const float al = __shfl(alpha, ab + 4 * e4 + q, 64);
                const uint4 hv = *reinterpret_cast<const uint4*>(
                    &h16[(size_t)snq * C_FEATS + cl * 8]);
                acc[0] = fmaf(al, bf_lo(hv.x), acc[0]);
                acc[1] = fmaf(al, bf_hi(hv.x), acc[1]);
                acc[2] = fmaf(al, bf_lo(hv.y), acc[2]);
                acc[3] = fmaf(al, bf_hi(hv.y), acc[3]);
                acc[4] = fmaf(al, bf_lo(hv.z), acc[4]);
                acc[5] = fmaf(al, bf_hi(hv.z), acc[5]);
                acc[6] = fmaf(al, bf_lo(hv.w), acc[6]);
                acc[7] = fmaf(al, bf_hi(hv.w), acc[7]);
            }
        }
    }

#pragma unroll
    for (int k = 0; k < 8; ++k) {
        acc[k] += __shfl_xor(acc[k], 16, 64);
        acc[k] += __shfl_xor(acc[k], 32, 64);
    }
    if (q == 0) {
        const float4 b0 = *reinterpret_cast<const float4*>(&bias[cl * 8]);
        const float4 b1 = *reinterpret_cast<const float4*>(&bias[cl * 8 + 4]);
        float4 o0 = make_float4(acc[0] + b0.x, acc[1] + b0.y, acc[2] + b0.z, acc[3] + b0.w);
        float4 o1 = make_float4(acc[4] + b1.x, acc[5] + b1.y, acc[6] + b1.z, acc[7] + b1.w);
        *reinterpret_cast<float4*>(&out[(size_t)n * C_FEATS + cl * 8]) = o0;
        *reinterpret_cast<float4*>(&out[(size_t)n * C_FEATS + cl * 8 + 4]) = o1;
    }
}

extern "C" void kernel_launch(void* const* d_in, const int* in_sizes, int n_in,
                              void* d_out, int out_size, void* d_ws, size_t ws_size,
                              hipStream_t stream) {
    const float* feat = (const float*)d_in[0];
    const float* W    = (const float*)d_in[1];
    const float* aw   = (const float*)d_in[2];
    const float* bias = (const float*)d_in[3];
    const int*   src  = (const int*)d_in[4];
    const int*   dst  = (const int*)d_in[5];
    float* out = (float*)d_out;

    const int N = in_sizes[0] / C_FEATS;
    const int E = in_sizes[4];
    const int NB = (N + 255) / 256;          // 196 (<= 256 for k_scanb)
    const int GB = (N + 127) / 128;          // gemm blocks (391)
    const int DB = 256;                      // degree-count blocks (x512 thr)
    const int LB = (N * H_HEADS + 255) / 256;// logits blocks (1563)

    char* p = (char*)d_ws;
    auto take = [&](size_t bytes) {
        char* q = p;
        p += (bytes + 255) & ~size_t(255);
        return q;
    };
    unsigned short* h16 = (unsigned short*)take((size_t)N * C_FEATS * 2);
    float* es      = (float*)take((size_t)N * H_HEADS * 4);
    float* edt     = (float*)take((size_t)N * H_HEADS * 4);
    int*   deg     = (int*)take((size_t)N * 4);
    int*   offs    = (int*)take((size_t)(N + 1) * 4);
    int*   cursor  = (int*)take((size_t)N * 4);
    int*   bsum    = (int*)take((size_t)NB * 4);
    int*   bpre    = (int*)take((size_t)NB * 4);
    int*   ssorted = (int*)take((size_t)E * 4);
    unsigned short* Wfh = (unsigned short*)take((size_t)C_FEATS * C_FEATS * 2);
    unsigned short* Wfl = (unsigned short*)take((size_t)C_FEATS * C_FEATS * 2);
    (void)ws_size;

    k_prep<<<8 + NB, 256, 0, stream>>>(W, Wfh, Wfl, deg, N);
    k_gemm_deg<<<DB + GB, 512, 0, stream>>>(feat, Wfh, Wfl, dst, deg, h16, N, E, DB);
    k_logits_bsum<<<LB + NB, 256, 0, stream>>>(h16, aw, es, edt, deg, bsum, N, LB);
    k_scanb<<<1, 256, 0, stream>>>(bsum, bpre, NB, offs, N);
    k_scanc<<<NB, 256, 0, stream>>>(deg, bpre, offs, cursor, N);
    k_scatter<<<(E + 255) / 256, 256, 0, stream>>>(src, dst, cursor, ssorted, E);
    k_agg<<<(N + 3) / 4, 256, 0, stream>>>(h16, es, edt, offs, ssorted, bias, out, N);
}

// Round 10
// 119.593 us; speedup vs baseline: 2.1131x; 1.2552x over previous
//
#include <hip/hip_runtime.h>
#include <hip/hip_bf16.h>

#define H_HEADS 8
#define D_OUT 16
#define C_FEATS 128          // H*D = in-feats = 128
#define NEG_SLOPE 0.2f

typedef __attribute__((ext_vector_type(8))) short short8;
typedef __attribute__((ext_vector_type(4))) float f32x4;

__device__ inline unsigned short f2bf(float f) {
    __hip_bfloat16 b = __float2bfloat16(f);
    return *reinterpret_cast<unsigned short*>(&b);
}
__device__ inline float bf2f(unsigned short u) {
    return __uint_as_float((unsigned)u << 16);
}
__device__ inline float bf_lo(unsigned u) { return __uint_as_float(u << 16); }
__device__ inline float bf_hi(unsigned u) { return __uint_as_float(u & 0xffff0000u); }

// ---------------- prologue: W -> split-bf16 fragment layout; zero deg -------
__global__ __launch_bounds__(256) void k_prep(const float* __restrict__ W,
                                              unsigned short* __restrict__ Wfh,
                                              unsigned short* __restrict__ Wfl,
                                              int* __restrict__ deg, int N) {
    const int b = blockIdx.x, t = threadIdx.x;
    if (b < 8) {
        const int idx = b * 256 + t;          // 0..2047 = 32 frags x 64 lanes
        const int frag = idx >> 6, lane = idx & 63;
        const int kc = frag >> 3, nt = frag & 7;
        const int kb = kc * 32 + ((lane >> 4) << 3);
        const int col = nt * 16 + (lane & 15);
        unsigned short hs[8], ls[8];
#pragma unroll
        for (int i = 0; i < 8; ++i) {
            const float x = W[(size_t)(kb + i) * C_FEATS + col];
            const unsigned short hh = f2bf(x);
            hs[i] = hh;
            ls[i] = f2bf(x - bf2f(hh));
        }
        uint4 uh, ul;
        uh.x = hs[0] | ((unsigned)hs[1] << 16);
        uh.y = hs[2] | ((unsigned)hs[3] << 16);
        uh.z = hs[4] | ((unsigned)hs[5] << 16);
        uh.w = hs[6] | ((unsigned)hs[7] << 16);
        ul.x = ls[0] | ((unsigned)ls[1] << 16);
        ul.y = ls[2] | ((unsigned)ls[3] << 16);
        ul.z = ls[4] | ((unsigned)ls[5] << 16);
        ul.w = ls[6] | ((unsigned)ls[7] << 16);
        *reinterpret_cast<uint4*>(&Wfh[(size_t)idx * 8]) = uh;
        *reinterpret_cast<uint4*>(&Wfl[(size_t)idx * 8]) = ul;
    } else {
        const int i = (b - 8) * 256 + t;
        if (i < N) deg[i] = 0;
    }
}

// ---------------- MFMA GEMM, LDS-staged W (+ fused degree+rank count) -------
// deg blocks: rank[e] = old count -> each edge learns its slot within its
// dst node; the later scatter needs no atomics. gemm blocks: 512 thr = 8
// waves, 128 rows/block, W staged in LDS, 3-term split-bf16 MFMA.
__global__ __launch_bounds__(512) void k_gemm_deg(
    const float* __restrict__ feat, const unsigned short* __restrict__ Wfh,
    const unsigned short* __restrict__ Wfl, const int* __restrict__ dst,
    int* __restrict__ deg, int* __restrict__ rank, unsigned short* __restrict__ h16,
    int N, int E, int degBlocks) {
    const int t = threadIdx.x;
    if ((int)blockIdx.x < degBlocks) {
        const int stride = degBlocks * 512;
        for (int e = blockIdx.x * 512 + t; e < E; e += stride)
            rank[e] = atomicAdd(&deg[dst[e]], 1);
        return;
    }
    __shared__ uint4 sW[4096];                 // [0,2048): Wfh  [2048,4096): Wfl
    {
        const uint4* gh = reinterpret_cast<const uint4*>(Wfh);
        const uint4* gl = reinterpret_cast<const uint4*>(Wfl);
#pragma unroll
        for (int i = 0; i < 4; ++i) {
            const int j = t + i * 512;
            sW[j] = gh[j];
            sW[j + 2048] = gl[j];
        }
    }
    __syncthreads();

    const int bid = blockIdx.x - degBlocks;
    const int w = t >> 6, lane = t & 63;
    const int rbase = bid * 128 + w * 16;
    const int rowA = rbase + (lane & 15);
    const int ko = (lane >> 4) << 3;
    const bool rv = rowA < N;
    const float* fr = feat + (size_t)rowA * C_FEATS;

    f32x4 acc[8];
#pragma unroll
    for (int nt = 0; nt < 8; ++nt)
#pragma unroll
        for (int j = 0; j < 4; ++j) acc[nt][j] = 0.f;

#pragma unroll
    for (int kc = 0; kc < 4; ++kc) {
        float4 x0 = make_float4(0.f, 0.f, 0.f, 0.f), x1 = x0;
        if (rv) {
            x0 = *reinterpret_cast<const float4*>(fr + kc * 32 + ko);
            x1 = *reinterpret_cast<const float4*>(fr + kc * 32 + ko + 4);
        }
        const float xs[8] = {x0.x, x0.y, x0.z, x0.w, x1.x, x1.y, x1.z, x1.w};
        short8 ah, al;
#pragma unroll
        for (int i = 0; i < 8; ++i) {
            const unsigned short hh = f2bf(xs[i]);
            ah[i] = (short)hh;
            al[i] = (short)f2bf(xs[i] - bf2f(hh));
        }
#pragma unroll
        for (int nt = 0; nt < 8; ++nt) {
            const int fi = (kc * 8 + nt) * 64 + lane;
            const short8 bh = *reinterpret_cast<const short8*>(&sW[fi]);
            const short8 bl = *reinterpret_cast<const short8*>(&sW[fi + 2048]);
            acc[nt] = __builtin_amdgcn_mfma_f32_16x16x32_bf16(ah, bh, acc[nt], 0, 0, 0);
            acc[nt] = __builtin_amdgcn_mfma_f32_16x16x32_bf16(al, bh, acc[nt], 0, 0, 0);
            acc[nt] = __builtin_amdgcn_mfma_f32_16x16x32_bf16(ah, bl, acc[nt], 0, 0, 0);
        }
    }
    // C layout (verified): col = lane&15, row = (lane>>4)*4 + reg
    const int r0 = rbase + ((lane >> 4) << 2);
    const int colc = lane & 15;
#pragma unroll
    for (int nt = 0; nt < 8; ++nt) {
#pragma unroll
        for (int r = 0; r < 4; ++r) {
            const int row = r0 + r;
            if (row < N)
                h16[(size_t)row * C_FEATS + nt * 16 + colc] = f2bf(acc[nt][r]);
        }
    }
}

// ---------------- logits (from h16) + bsum fused ----------------
__global__ __launch_bounds__(256) void k_logits_bsum(
    const unsigned short* __restrict__ h16, const float* __restrict__ aw,
    float* __restrict__ es, float* __restrict__ ed,
    const int* __restrict__ deg, int* __restrict__ bsum, int N, int LB) {
    const int t = threadIdx.x;
    if ((int)blockIdx.x < LB) {
        const int idx = blockIdx.x * 256 + t;
        if (idx >= N * H_HEADS) return;
        const int n = idx >> 3, hh = idx & 7;
        const uint4 u0 = *reinterpret_cast<const uint4*>(&h16[(size_t)n * C_FEATS + hh * 16]);
        const uint4 u1 = *reinterpret_cast<const uint4*>(&h16[(size_t)n * C_FEATS + hh * 16 + 8]);
        float hv[16];
        hv[0] = bf_lo(u0.x);  hv[1] = bf_hi(u0.x);
        hv[2] = bf_lo(u0.y);  hv[3] = bf_hi(u0.y);
        hv[4] = bf_lo(u0.z);  hv[5] = bf_hi(u0.z);
        hv[6] = bf_lo(u0.w);  hv[7] = bf_hi(u0.w);
        hv[8] = bf_lo(u1.x);  hv[9] = bf_hi(u1.x);
        hv[10] = bf_lo(u1.y); hv[11] = bf_hi(u1.y);
        hv[12] = bf_lo(u1.z); hv[13] = bf_hi(u1.z);
        hv[14] = bf_lo(u1.w); hv[15] = bf_hi(u1.w);
        float s0 = 0.f, s1 = 0.f;
#pragma unroll
        for (int j = 0; j < 16; ++j) {
            s0 = fmaf(hv[j], aw[hh * 16 + j], s0);
            s1 = fmaf(hv[j], aw[C_FEATS + hh * 16 + j], s1);
        }
        es[idx] = s0;
        ed[idx] = s1;
    } else {
        const int i = (blockIdx.x - LB) * 256 + t;
        int v = (i < N) ? deg[i] : 0;
#pragma unroll
        for (int m = 1; m < 64; m <<= 1) v += __shfl_xor(v, m, 64);
        __shared__ int ws[4];
        if ((t & 63) == 0) ws[t >> 6] = v;
        __syncthreads();
        if (t == 0) bsum[blockIdx.x - LB] = ws[0] + ws[1] + ws[2] + ws[3];
    }
}

// ---------------- scan helpers ----------------
__device__ inline int block_scan_incl(int v) {
    int lane = threadIdx.x & 63, w = threadIdx.x >> 6;
    int x = v;
#pragma unroll
    for (int d = 1; d < 64; d <<= 1) {
        int u = __shfl_up(x, d, 64);
        if (lane >= d) x += u;
    }
    __shared__ int wsum[4];
    if (lane == 63) wsum[w] = x;
    __syncthreads();
    int add = 0;
    for (int k = 0; k < w; ++k) add += wsum[k];
    return x + add;
}

__global__ void k_scanb(const int* __restrict__ bsum, int* __restrict__ bpre,
                        int NB, int* __restrict__ offs, int N) {
    int t = threadIdx.x;
    int v = (t < NB) ? bsum[t] : 0;
    int incl = block_scan_incl(v);
    if (t < NB) bpre[t] = incl - v;
    if (t == NB - 1) offs[N] = incl;
}

__global__ void k_scanc(const int* __restrict__ deg, const int* __restrict__ bpre,
                        int* __restrict__ offs, int N) {
    int i = blockIdx.x * 256 + threadIdx.x;
    int v = (i < N) ? deg[i] : 0;
    int incl = block_scan_incl(v);
    int excl = incl - v + bpre[blockIdx.x];
    if (i < N) offs[i] = excl;
}

// ---------------- scatter: atomic-free via precomputed ranks ----------------
__global__ void k_scatter(const int* __restrict__ src, const int* __restrict__ dst,
                          const int* __restrict__ rank, const int* __restrict__ offs,
                          int* __restrict__ ssorted, int E) {
    int e = blockIdx.x * 256 + threadIdx.x;
    if (e < E)
        ssorted[offs[dst[e]] + rank[e]] = src[e];
}

// ---------------- two-pass softmax + aggregation (R8-proven, untouched) -----
__global__ __launch_bounds__(256) void k_agg(const unsigned short* __restrict__ h16,
                                             const float* __restrict__ es,
                                             const float* __restrict__ ed,
                                             const int* __restrict__ offs,
                                             const int* __restrict__ ssorted,
                                             const float* __restrict__ bias,
                                             float* __restrict__ out, int N) {
    const int wid = threadIdx.x >> 6, lane = threadIdx.x & 63;
    const int n = blockIdx.x * 4 + wid;
    if (n >= N) return;
    const int beg = offs[n];
    const int deg = offs[n + 1] - beg;

    const int hh = lane >> 3, j0 = lane & 7;
    const float edv = ed[(size_t)n * H_HEADS + hh];

    const int cl = lane & 15, q = lane >> 4;
    const int ah = cl >> 1;             // head owning this lane's 8 columns
    const int ab = ah << 3;             // softmax-layout base lane for head ah
    float acc[8];
#pragma unroll
    for (int k = 0; k < 8; ++k) acc[k] = 0.f;

    float m = -1e30f, s = 0.f;

    if (deg <= 32) {
        // ---------- cached fast path ----------
        int snc[4];
        float evc[4];
#pragma unroll
        for (int c = 0; c < 4; ++c) {
            const int j = c * 8 + j0;
            const bool va = (j < deg);
            int sn = 0;
            float ev = -1e30f;
            if (va) {
                sn = ssorted[beg + j];
                float t = es[(size_t)sn * H_HEADS + hh] + edv;
                ev = t > 0.f ? t : NEG_SLOPE * t;
                if (ev > m) {
                    s = s * __expf(m - ev) + 1.f;
                    m = ev;
                } else {
                    s += __expf(ev - m);
                }
            }
            snc[c] = sn;
            evc[c] = ev;
        }
#pragma unroll
        for (int msk = 1; msk < 8; msk <<= 1) {
            float mo = __shfl_xor(m, msk, 64);
            float so = __shfl_xor(s, msk, 64);
            float mn = fmaxf(m, mo);
            s = s * __expf(m - mn) + so * __expf(mo - mn);
            m = mn;
        }
        const float inv = (s > 0.f) ? 1.f / s : 0.f;

#pragma unroll
        for (int c = 0; c < 4; ++c) {
            const int cb = c * 8;
            if (cb >= deg) break;                 // wave-uniform exit
            const float alpha = (cb + j0 < deg) ? __expf(evc[c] - m) * inv : 0.f;
            const int sn = snc[c];
            int rem = deg - cb; if (rem > 8) rem = 8;
#pragma unroll
            for (int e4 = 0; e4 < 2; ++e4) {
                if (4 * e4 >= rem) break;         // wave-uniform exit
                const int s0 = __shfl(sn, 4 * e4 + 0, 64);
                const int s1 = __shfl(sn, 4 * e4 + 1, 64);
                const int s2 = __shfl(sn, 4 * e4 + 2, 64);
                const int s3 = __shfl(sn, 4 * e4 + 3, 64);
                const int snq = (q == 0) ? s0 : (q == 1) ? s1 : (q == 2) ? s2 : s3;
                const float al = __shfl(alpha, ab + 4 * e4 + q, 64);
                const uint4 hv = *reinterpret_cast<const uint4*>(
                    &h16[(size_t)snq * C_FEATS + cl * 8]);
                acc[0] = fmaf(al, bf_lo(hv.x), acc[0]);
                acc[1] = fmaf(al, bf_hi(hv.x), acc[1]);
                acc[2] = fmaf(al, bf_lo(hv.y), acc[2]);
                acc[3] = fmaf(al, bf_hi(hv.y), acc[3]);
                acc[4] = fmaf(al, bf_lo(hv.z), acc[4]);
                acc[5] = fmaf(al, bf_hi(hv.z), acc[5]);
                acc[6] = fmaf(al, bf_lo(hv.w), acc[6]);
                acc[7] = fmaf(al, bf_hi(hv.w), acc[7]);
            }
        }
    } else {
        // ---------- streaming fallback ----------
        for (int e = j0; e < deg; e += 8) {
            int sn = ssorted[beg + e];
            float ev = es[(size_t)sn * H_HEADS + hh] + edv;
            ev = ev > 0.f ? ev : NEG_SLOPE * ev;
            if (ev > m) {
                s = s * __expf(m - ev) + 1.f;
                m = ev;
            } else {
                s += __expf(ev - m);
            }
        }
#pragma unroll
        for (int msk = 1; msk < 8; msk <<= 1) {
            float mo = __shfl_xor(m, msk, 64);
            float so = __shfl_xor(s, msk, 64);
            float mn = fmaxf(m, mo);
            s = s * __expf(m - mn) + so * __expf(mo - mn);
            m = mn;
        }
        const float inv = (s > 0.f) ? 1.f / s : 0.f;

        for (int cb = 0; cb < deg; cb += 8) {
            const int j = cb + j0;
            int sn = 0;
            float alpha = 0.f;
            if (j < deg) {
                sn = ssorted[beg + j];
                float t = es[(size_t)sn * H_HEADS + hh] + edv;
                t = t > 0.f ? t : NEG_SLOPE * t;
                alpha = __expf(t - m) * inv;
            }
            int rem = deg - cb; if (rem > 8) rem = 8;
#pragma unroll
            for (int e4 = 0; e4 < 2; ++e4) {
                if (4 * e4 >= rem) break;
                const int s0 = __shfl(sn, 4 * e4 + 0, 64);
                const int s1 = __shfl(sn, 4 * e4 + 1, 64);
                const int s2 = __shfl(sn, 4 * e4 + 2, 64);
                const int s3 = __shfl(sn, 4 * e4 + 3, 64);
                const int snq = (q == 0) ? s0 : (q == 1) ? s1 : (q == 2) ? s2 : s3;
                const float al = __shfl(alpha, ab + 4 * e4 + q, 64);
                const uint4 hv = *reinterpret_cast<const uint4*>(
                    &h16[(size_t)snq * C_FEATS + cl * 8]);
                acc[0] = fmaf(al, bf_lo(hv.x), acc[0]);
                acc[1] = fmaf(al, bf_hi(hv.x), acc[1]);
                acc[2] = fmaf(al, bf_lo(hv.y), acc[2]);
                acc[3] = fmaf(al, bf_hi(hv.y), acc[3]);
                acc[4] = fmaf(al, bf_lo(hv.z), acc[4]);
                acc[5] = fmaf(al, bf_hi(hv.z), acc[5]);
                acc[6] = fmaf(al, bf_lo(hv.w), acc[6]);
                acc[7] = fmaf(al, bf_hi(hv.w), acc[7]);
            }
        }
    }

#pragma unroll
    for (int k = 0; k < 8; ++k) {
        acc[k] += __shfl_xor(acc[k], 16, 64);
        acc[k] += __shfl_xor(acc[k], 32, 64);
    }
    if (q == 0) {
        const float4 b0 = *reinterpret_cast<const float4*>(&bias[cl * 8]);
        const float4 b1 = *reinterpret_cast<const float4*>(&bias[cl * 8 + 4]);
        float4 o0 = make_float4(acc[0] + b0.x, acc[1] + b0.y, acc[2] + b0.z, acc[3] + b0.w);
        float4 o1 = make_float4(acc[4] + b1.x, acc[5] + b1.y, acc[6] + b1.z, acc[7] + b1.w);
        *reinterpret_cast<float4*>(&out[(size_t)n * C_FEATS + cl * 8]) = o0;
        *reinterpret_cast<float4*>(&out[(size_t)n * C_FEATS + cl * 8 + 4]) = o1;
    }
}

extern "C" void kernel_launch(void* const* d_in, const int* in_sizes, int n_in,
                              void* d_out, int out_size, void* d_ws, size_t ws_size,
                              hipStream_t stream) {
    const float* feat = (const float*)d_in[0];
    const float* W    = (const float*)d_in[1];
    const float* aw   = (const float*)d_in[2];
    const float* bias = (const float*)d_in[3];
    const int*   src  = (const int*)d_in[4];
    const int*   dst  = (const int*)d_in[5];
    float* out = (float*)d_out;

    const int N = in_sizes[0] / C_FEATS;
    const int E = in_sizes[4];
    const int NB = (N + 255) / 256;          // 196 (<= 256 for k_scanb)
    const int GB = (N + 127) / 128;          // gemm blocks (391)
    const int DB = 256;                      // degree-count blocks (x512 thr)
    const int LB = (N * H_HEADS + 255) / 256;// logits blocks (1563)

    char* p = (char*)d_ws;
    auto take = [&](size_t bytes) {
        char* q = p;
        p += (bytes + 255) & ~size_t(255);
        return q;
    };
    unsigned short* h16 = (unsigned short*)take((size_t)N * C_FEATS * 2);
    float* es      = (float*)take((size_t)N * H_HEADS * 4);
    float* edt     = (float*)take((size_t)N * H_HEADS * 4);
    int*   deg     = (int*)take((size_t)N * 4);
    int*   offs    = (int*)take((size_t)(N + 1) * 4);
    int*   bsum    = (int*)take((size_t)NB * 4);
    int*   bpre    = (int*)take((size_t)NB * 4);
    int*   ssorted = (int*)take((size_t)E * 4);
    int*   rank    = (int*)take((size_t)E * 4);
    unsigned short* Wfh = (unsigned short*)take((size_t)C_FEATS * C_FEATS * 2);
    unsigned short* Wfl = (unsigned short*)take((size_t)C_FEATS * C_FEATS * 2);
    (void)ws_size;

    k_prep<<<8 + NB, 256, 0, stream>>>(W, Wfh, Wfl, deg, N);
    k_gemm_deg<<<DB + GB, 512, 0, stream>>>(feat, Wfh, Wfl, dst, deg, rank, h16, N, E, DB);
    k_logits_bsum<<<LB + NB, 256, 0, stream>>>(h16, aw, es, edt, deg, bsum, N, LB);
    k_scanb<<<1, 256, 0, stream>>>(bsum, bpre, NB, offs, N);
    k_scanc<<<NB, 256, 0, stream>>>(deg, bpre, offs, N);
    k_scatter<<<(E + 255) / 256, 256, 0, stream>>>(src, dst, rank, offs, ssorted, E);
    k_agg<<<(N + 3) / 4, 256, 0, stream>>>(h16, es, edt, offs, ssorted, bias, out, N);
}